// Round 3
// baseline (184.846 us; speedup 1.0000x reference)
//
#include <hip/hip_runtime.h>

// Problem constants
constexpr int Bn = 2;
constexpr int Sn = 2048;
constexpr int En = 512;
constexpr int Hn = 8;
constexpr int Dn = 64;
constexpr int Mn = Bn * Sn;              // 4096 rows

typedef short bf8 __attribute__((ext_vector_type(8)));
typedef float f32x4 __attribute__((ext_vector_type(4)));

// element counts (ushort units) for the bf16 workspace region
constexpr size_t XY = (size_t)Mn * En;          // 2,097,152  x planes
constexpr size_t WT = (size_t)3 * En * En;      //   786,432  Wqkv transposed planes
constexpr size_t WP = (size_t)En * En;          //   262,144  Wp planes
constexpr size_t PL = (size_t)Bn * Hn * Sn * Dn;// 2,097,152  q/k/v planes

__device__ __forceinline__ unsigned short f2bf(float f) {
    unsigned int u = __float_as_uint(f);
    unsigned int r = 0x7FFFu + ((u >> 16) & 1u);
    return (unsigned short)((u + r) >> 16);
}
__device__ __forceinline__ float bf2f(unsigned short u) {
    return __uint_as_float(((unsigned int)u) << 16);
}
__device__ __forceinline__ void split2(float f, unsigned short& hi, unsigned short& lo) {
    hi = f2bf(f);
    lo = f2bf(f - bf2f(hi));
}

// global -> LDS direct copy, 16 B per lane. LDS dest is wave-uniform base +
// lane*16 (HW behavior); global source is per-lane.
__device__ __forceinline__ void g2l16(const unsigned short* g, unsigned short* l) {
    typedef __attribute__((address_space(1))) const unsigned int gu32;
    typedef __attribute__((address_space(3))) unsigned int lu32;
    __builtin_amdgcn_global_load_lds((gu32*)(unsigned long long)g,
                                     (lu32*)(unsigned int)(unsigned long long)l,
                                     16, 0, 0);
}

// ---------------------------------------------------------------------------
// Prep (fused): blocks [0,1024) presplit x; [1024,1152) presplit Wp;
// [1152,1344) transpose+split Wq/Wk/Wv -> Wt[n][k]. (R9-exact)
// ---------------------------------------------------------------------------
__global__ __launch_bounds__(256)
void prep(const float* __restrict__ x, const float* __restrict__ Wp,
          const float* __restrict__ Wq, const float* __restrict__ Wk,
          const float* __restrict__ Wv,
          unsigned short* __restrict__ xh, unsigned short* __restrict__ xl,
          unsigned short* __restrict__ Wph, unsigned short* __restrict__ Wpl,
          unsigned short* __restrict__ Wth, unsigned short* __restrict__ Wtl)
{
    __shared__ float t[64][65];
    const int bid = blockIdx.x;
    const int tid = threadIdx.x;

    if (bid < 1152) {
        const float* src = (bid < 1024) ? x : Wp;
        unsigned short* hp = (bid < 1024) ? xh : Wph;
        unsigned short* lp = (bid < 1024) ? xl : Wpl;
        const int blk = (bid < 1024) ? bid : (bid - 1024);
        const size_t base = ((size_t)blk * 256 + tid) * 8;
        float a[8];
        *(float4*)&a[0] = *(const float4*)(src + base);
        *(float4*)&a[4] = *(const float4*)(src + base + 4);
        unsigned short h[8], l[8];
        #pragma unroll
        for (int j = 0; j < 8; ++j) split2(a[j], h[j], l[j]);
        *(bf8*)(hp + base) = *(bf8*)&h[0];
        *(bf8*)(lp + base) = *(bf8*)&l[0];
        return;
    }

    const int idx = bid - 1152;           // 0..191
    const int ph = idx >> 3;              // 0..23
    const int proj = ph >> 3, h = ph & 7;
    const int e0 = (idx & 7) * 64;
    const float* W = (proj == 0) ? Wq : (proj == 1) ? Wk : Wv;
    const float* src = W + (size_t)h * En * Dn + (size_t)e0 * Dn;

    const int er = tid >> 2, cg = (tid & 3) * 16;
    #pragma unroll
    for (int c = 0; c < 4; ++c) {
        float4 v = *(const float4*)(src + (size_t)er * Dn + cg + 4 * c);
        t[er][cg + 4 * c + 0] = v.x;
        t[er][cg + 4 * c + 1] = v.y;
        t[er][cg + 4 * c + 2] = v.z;
        t[er][cg + 4 * c + 3] = v.w;
    }
    __syncthreads();

    const int d = tid >> 2, jg = (tid & 3) * 16;
    unsigned short h16[16], l16[16];
    #pragma unroll
    for (int j = 0; j < 16; ++j) split2(t[jg + j][d], h16[j], l16[j]);
    const size_t n = (size_t)proj * 512 + h * 64 + d;
    unsigned short* dh = Wth + n * En + e0 + jg;
    unsigned short* dl = Wtl + n * En + e0 + jg;
    *(bf8*)dh       = *(bf8*)&h16[0];
    *(bf8*)(dh + 8) = *(bf8*)&h16[8];
    *(bf8*)dl       = *(bf8*)&l16[0];
    *(bf8*)(dl + 8) = *(bf8*)&l16[8];
}

// ---------------------------------------------------------------------------
// Kernel 1 (R11-exact): fused QKV projection, 128x64 tiles, global_load_lds
// width-16 staging into linear LDS tiles. Grid (32,24)=768 -> 3/CU.
// ---------------------------------------------------------------------------
__global__ __launch_bounds__(256)
void qkv_gemm(const unsigned short* __restrict__ xh,
              const unsigned short* __restrict__ xl,
              const unsigned short* __restrict__ Wth,
              const unsigned short* __restrict__ Wtl,
              unsigned short* __restrict__ qh_g,
              unsigned short* __restrict__ ql_g,
              unsigned short* __restrict__ kh_g,
              unsigned short* __restrict__ kl_g,
              unsigned short* __restrict__ vT_g)
{
    __shared__ __align__(16) unsigned char smraw[24576];
    unsigned short* ldsAh = (unsigned short*)smraw;          // [128][32]
    unsigned short* ldsAl = ldsAh + 4096;
    unsigned short* ldsBh = ldsAl + 4096;                    // [64][32]
    unsigned short* ldsBl = ldsBh + 2048;
    float (*Cf)[68] = (float(*)[68])(smraw);   // 64 x 68 fp32 (epilogue)

    const int tid = threadIdx.x;
    const int m0 = blockIdx.x * 128;
    const int ny = blockIdx.y;            // 0..23
    const int proj = ny >> 3, h = ny & 7;

    const int wave = tid >> 6, lane = tid & 63;
    const int wm = (wave >> 1) * 64, wn = (wave & 1) * 32;
    const int lm = lane & 15, quad = lane >> 4;

    const int l4r = lane >> 2;            // 0..15
    const int l4c = (lane & 3) * 8;       // ushort col
    const unsigned short* gAh0 = xh + (size_t)(m0 + wave * 32 + l4r) * En + l4c;
    const unsigned short* gAh1 = gAh0 + (size_t)16 * En;
    const unsigned short* gAl0 = xl + (size_t)(m0 + wave * 32 + l4r) * En + l4c;
    const unsigned short* gAl1 = gAl0 + (size_t)16 * En;
    const unsigned short* gBh  = Wth + (size_t)(ny * 64 + wave * 16 + l4r) * En + l4c;
    const unsigned short* gBl  = Wtl + (size_t)(ny * 64 + wave * 16 + l4r) * En + l4c;
    unsigned short* dAh0 = ldsAh + wave * 1024;
    unsigned short* dAh1 = dAh0 + 512;
    unsigned short* dAl0 = ldsAl + wave * 1024;
    unsigned short* dAl1 = dAl0 + 512;
    unsigned short* dBh  = ldsBh + wave * 512;
    unsigned short* dBl  = ldsBl + wave * 512;

    f32x4 acc[4][2];
    #pragma unroll
    for (int i = 0; i < 4; ++i)
        #pragma unroll
        for (int j = 0; j < 2; ++j) acc[i][j] = (f32x4){0.f, 0.f, 0.f, 0.f};

    for (int k0 = 0; k0 < En; k0 += 32) {
        g2l16(gAh0 + k0, dAh0);
        g2l16(gAh1 + k0, dAh1);
        g2l16(gAl0 + k0, dAl0);
        g2l16(gAl1 + k0, dAl1);
        g2l16(gBh + k0, dBh);
        g2l16(gBl + k0, dBl);
        __syncthreads();

        bf8 a_h[4], a_l[4], b_h[2], b_l[2];
        #pragma unroll
        for (int mi = 0; mi < 4; ++mi) {
            a_h[mi] = *(const bf8*)(ldsAh + (wm + mi * 16 + lm) * 32 + quad * 8);
            a_l[mi] = *(const bf8*)(ldsAl + (wm + mi * 16 + lm) * 32 + quad * 8);
        }
        #pragma unroll
        for (int ni = 0; ni < 2; ++ni) {
            b_h[ni] = *(const bf8*)(ldsBh + (wn + ni * 16 + lm) * 32 + quad * 8);
            b_l[ni] = *(const bf8*)(ldsBl + (wn + ni * 16 + lm) * 32 + quad * 8);
        }
        #pragma unroll
        for (int mi = 0; mi < 4; ++mi)
            #pragma unroll
            for (int ni = 0; ni < 2; ++ni) {
                acc[mi][ni] = __builtin_amdgcn_mfma_f32_16x16x32_bf16(a_h[mi], b_h[ni], acc[mi][ni], 0, 0, 0);
                acc[mi][ni] = __builtin_amdgcn_mfma_f32_16x16x32_bf16(a_h[mi], b_l[ni], acc[mi][ni], 0, 0, 0);
                acc[mi][ni] = __builtin_amdgcn_mfma_f32_16x16x32_bf16(a_l[mi], b_h[ni], acc[mi][ni], 0, 0, 0);
            }
        __syncthreads();
    }

    if (proj < 2) {
        unsigned short* hp = (proj == 0) ? qh_g : kh_g;
        unsigned short* lp = (proj == 0) ? ql_g : kl_g;
        #pragma unroll
        for (int p = 0; p < 2; ++p) {
            if ((wave >> 1) == p) {
                #pragma unroll
                for (int mi = 0; mi < 4; ++mi)
                    #pragma unroll
                    for (int ni = 0; ni < 2; ++ni)
                        #pragma unroll
                        for (int r = 0; r < 4; ++r)
                            Cf[mi * 16 + quad * 4 + r][wn + ni * 16 + lm] = acc[mi][ni][r];
            }
            __syncthreads();
            {
                const int lr = tid & 63;
                const int cg = (tid >> 6) * 16;   // wave-uniform d-chunk
                const int m = m0 + p * 64 + lr;
                const int b = m >> 11, s = m & 2047;
                unsigned short hi[16], lo[16];
                #pragma unroll
                for (int j4 = 0; j4 < 4; ++j4) {
                    float4 v = *(const float4*)&Cf[lr][cg + 4 * j4];
                    split2(v.x, hi[4 * j4 + 0], lo[4 * j4 + 0]);
                    split2(v.y, hi[4 * j4 + 1], lo[4 * j4 + 1]);
                    split2(v.z, hi[4 * j4 + 2], lo[4 * j4 + 2]);
                    split2(v.w, hi[4 * j4 + 3], lo[4 * j4 + 3]);
                }
                const size_t base = (((size_t)(b * Hn + h) * Sn + s) * Dn) + cg;
                *(bf8*)(hp + base)     = *(bf8*)&hi[0];
                *(bf8*)(hp + base + 8) = *(bf8*)&hi[8];
                *(bf8*)(lp + base)     = *(bf8*)&lo[0];
                *(bf8*)(lp + base + 8) = *(bf8*)&lo[8];
            }
            __syncthreads();
        }
    } else {
        #pragma unroll
        for (int mi = 0; mi < 4; ++mi) {
            const int s0 = m0 + wm + mi * 16 + quad * 4;
            const int b = s0 >> 11, s = s0 & 2047;
            #pragma unroll
            for (int ni = 0; ni < 2; ++ni) {
                const int d = wn + ni * 16 + lm;
                ushort4 pk;
                pk.x = f2bf(acc[mi][ni][0]);
                pk.y = f2bf(acc[mi][ni][1]);
                pk.z = f2bf(acc[mi][ni][2]);
                pk.w = f2bf(acc[mi][ni][3]);
                *(ushort4*)(vT_g + ((size_t)(b * Hn + h) * Dn + d) * Sn + s) = pk;
            }
        }
    }
}

// ---------------------------------------------------------------------------
// Kernel 2 (R10-exact): MFMA flash attention, 2-way split-t, XCD-aware bh
// mapping, defer-max (THR=12), setprio around MFMA clusters, tree max.
// ---------------------------------------------------------------------------
__global__ __launch_bounds__(256)
void attn(const unsigned short* __restrict__ qh_g,
          const unsigned short* __restrict__ ql_g,
          const unsigned short* __restrict__ kh_g,
          const unsigned short* __restrict__ kl_g,
          const unsigned short* __restrict__ vT_g,
          unsigned short* __restrict__ Op,
          float* __restrict__ ml)
{
    extern __shared__ unsigned short sm[];
    unsigned short (*khs)[72] = (unsigned short(*)[72])(sm);          // [t][d] hi
    unsigned short (*kls)[72] = (unsigned short(*)[72])(sm + 4608);   // [t][d] lo
    unsigned short (*vTs)[72] = (unsigned short(*)[72])(sm + 9216);   // [d][t]
    unsigned short (*pts)[72] = (unsigned short(*)[72])(sm + 13824);  // [q][t]
    float* alf = (float*)(sm + 18432);                                // [64]

    const int bidx = blockIdx.x;
    const int xcd = bidx & 7;
    const int g = bidx >> 3;              // 0..127
    const int bh = xcd * 2 + (g & 1);     // 2 bh per XCD
    const int rest = g >> 1;              // 0..63
    const int hf = rest >> 5;             // K-range half
    const int a_ = rest & 31;
    const int qt = hf ? (31 - a_) : a_;   // direction alternation for balance
    const int n0 = (qt + 2) >> 1;
    const int its = hf ? n0 : 0;
    const int ite = hf ? (qt + 1) : n0;
    const int pslot = hf * 512 + bh * 32 + qt;

    const int tid = threadIdx.x;
    const int wave = tid >> 6, lane = tid & 63;
    const int quad = lane >> 4, lq = lane & 15;

    const unsigned short* khb = kh_g + (size_t)bh * Sn * Dn;
    const unsigned short* klb = kl_g + (size_t)bh * Sn * Dn;
    const unsigned short* vTb = vT_g + (size_t)bh * Dn * Sn;

    bf8 qfh[2], qfl[2];
    {
        const size_t qoff = ((size_t)bh * Sn + (size_t)qt * 64 + wave * 16 + lq) * Dn;
        #pragma unroll
        for (int c = 0; c < 2; ++c) {
            qfh[c] = *(const bf8*)(qh_g + qoff + c * 32 + quad * 8);
            qfl[c] = *(const bf8*)(ql_g + qoff + c * 32 + quad * 8);
        }
    }

    f32x4 accO[4];
    #pragma unroll
    for (int nj = 0; nj < 4; ++nj) accO[nj] = (f32x4){0.f, 0.f, 0.f, 0.f};
    float m = -1e30f, l = 0.f;

    const int srow = tid & 63;
    const int sdg  = tid >> 6;

    bf8 pk0, pk1, pl0, pl1, pv0, pv1;
    if (its < ite) {
        const int t0 = its * 64;
        const unsigned short* kr = khb + (size_t)(t0 + srow) * Dn + sdg * 16;
        const unsigned short* lr = klb + (size_t)(t0 + srow) * Dn + sdg * 16;
        const unsigned short* vr = vTb + (size_t)srow * Sn + t0 + sdg * 16;
        pk0 = *(const bf8*)(kr);  pk1 = *(const bf8*)(kr + 8);
        pl0 = *(const bf8*)(lr);  pl1 = *(const bf8*)(lr + 8);
        pv0 = *(const bf8*)(vr);  pv1 = *(const bf8*)(vr + 8);
    }

    for (int it = its; it < ite; ++it) {
        __syncthreads();
        *(bf8*)&khs[srow][sdg * 16]     = pk0;
        *(bf8*)&khs[srow][sdg * 16 + 8] = pk1;
        *(bf8*)&kls[srow][sdg * 16]     = pl0;
        *(bf8*)&kls[srow][sdg * 16 + 8] = pl1;
        *(bf8*)&vTs[srow][sdg * 16]     = pv0;
        *(bf8*)&vTs[srow][sdg * 16 + 8] = pv1;
        __syncthreads();

        if (it + 1 < ite) {
            const int t1 = (it + 1) * 64;
            const unsigned short* kr = khb + (size_t)(t1 + srow) * Dn + sdg * 16;
            const unsigned short* lr = klb + (size_t)(t1 + srow) * Dn + sdg * 16;
            const unsigned short* vr = vTb + (size_t)srow * Sn + t1 + sdg * 16;
            pk0 = *(const bf8*)(kr);  pk1 = *(const bf8*)(kr + 8);
            pl0 = *(const bf8*)(lr);  pl1 = *(const bf8*)(lr + 8);
            pv0 = *(const bf8*)(vr);  pv1 = *(const bf8*)(vr + 8);
        }

        f32x4 accS[4];
        #pragma unroll
        for (int mi = 0; mi < 4; ++mi) accS[mi] = (f32x4){0.f, 0.f, 0.f, 0.f};
        __builtin_amdgcn_s_setprio(1);
        #pragma unroll
        for (int mi = 0; mi < 4; ++mi) {
            #pragma unroll
            for (int c = 0; c < 2; ++c) {
                bf8 ah = *(const bf8*)&khs[mi * 16 + lq][c * 32 + quad * 8];
                bf8 al = *(const bf8*)&kls[mi * 16 + lq][c * 32 + quad * 8];
                accS[mi] = __builtin_amdgcn_mfma_f32_16x16x32_bf16(ah, qfh[c], accS[mi], 0, 0, 0);
                accS[mi] = __builtin_amdgcn_mfma_f32_16x16x32_bf16(ah, qfl[c], accS[mi], 0, 0, 0);
                accS[mi] = __builtin_amdgcn_mfma_f32_16x16x32_bf16(al, qfh[c], accS[mi], 0, 0, 0);
            }
        }
        __builtin_amdgcn_s_setprio(0);

        if (it == qt) {
            const int qrel = wave * 16 + lq;
            #pragma unroll
            for (int mi = 0; mi < 4; ++mi)
                #pragma unroll
                for (int r = 0; r < 4; ++r)
                    if (mi * 16 + quad * 4 + r > qrel) accS[mi][r] = -INFINITY;
        }

        float mt;
        {
            float t0 = fmaxf(fmaxf(accS[0][0], accS[0][1]), fmaxf(accS[0][2], accS[0][3]));
            float t1 = fmaxf(fmaxf(accS[1][0], accS[1][1]), fmaxf(accS[1][2], accS[1][3]));
            float t2 = fmaxf(fmaxf(accS[2][0], accS[2][1]), fmaxf(accS[2][2], accS[2][3]));
            float t3 = fmaxf(fmaxf(accS[3][0], accS[3][1]), fmaxf(accS[3][2], accS[3][3]));
            mt = fmaxf(fmaxf(t0, t1), fmaxf(t2, t3));
        }
        mt = fmaxf(mt, __shfl_xor(mt, 16));
        mt = fmaxf(mt, __shfl_xor(mt, 32));

        const bool defer = __all(mt <= m + 12.f);
        float mref, alpha = 1.f;
        if (defer) {
            mref = m;
        } else {
            mref = fmaxf(m, mt);
            alpha = __expf(m - mref);
        }

        float ls = 0.f;
        #pragma unroll
        for (int mi = 0; mi < 4; ++mi)
            #pragma unroll
            for (int r = 0; r < 4; ++r) {
                const float p = __expf(accS[mi][r] - mref);
                accS[mi][r] = p;
                ls += p;
            }
        ls += __shfl_xor(ls, 16);
        ls += __shfl_xor(ls, 32);
        if (defer) {
            l += ls;
        } else {
            l = l * alpha + ls;
            m = mref;
        }

        #pragma unroll
        for (int mi = 0; mi < 4; ++mi) {
            ushort4 pk;
            pk.x = f2bf(accS[mi][0]);
            pk.y = f2bf(accS[mi][1]);
            pk.z = f2bf(accS[mi][2]);
            pk.w = f2bf(accS[mi][3]);
            *(ushort4*)&pts[wave * 16 + lq][mi * 16 + quad * 4] = pk;
        }

        if (!defer) {
            if (quad == 0) alf[wave * 16 + lq] = alpha;
            float4 al4 = *(const float4*)&alf[wave * 16 + quad * 4];
            #pragma unroll
            for (int nj = 0; nj < 4; ++nj) {
                accO[nj][0] *= al4.x;
                accO[nj][1] *= al4.y;
                accO[nj][2] *= al4.z;
                accO[nj][3] *= al4.w;
            }
        }

        __builtin_amdgcn_s_setprio(1);
        #pragma unroll
        for (int c = 0; c < 2; ++c) {
            bf8 pf = *(const bf8*)&pts[wave * 16 + lq][c * 32 + quad * 8];
            #pragma unroll
            for (int nj = 0; nj < 4; ++nj) {
                bf8 vf = *(const bf8*)&vTs[nj * 16 + lq][c * 32 + quad * 8];
                accO[nj] = __builtin_amdgcn_mfma_f32_16x16x32_bf16(pf, vf, accO[nj], 0, 0, 0);
            }
        }
        __builtin_amdgcn_s_setprio(0);
    }

    if (quad == 0) {
        const size_t mi_ = ((size_t)pslot * 64 + wave * 16 + lq) * 2;
        ml[mi_]     = m;
        ml[mi_ + 1] = l;
    }
    #pragma unroll
    for (int r = 0; r < 4; ++r) {
        const int q = wave * 16 + quad * 4 + r;
        unsigned short* dst = Op + ((size_t)pslot * 64 + q) * 64;
        #pragma unroll
        for (int nj = 0; nj < 4; ++nj)
            dst[nj * 16 + lq] = f2bf(accO[nj][r]);
    }
}

// ---------------------------------------------------------------------------
// Kernel 3 (R12, NEW): fused combine + out-projection + residual + LayerNorm.
// One block = 16 rows x full N=512, full K=512. Grid 256 (1/CU), 512 threads.
// B (Wp hi/lo) streamed via global_load_lds (64 KB/K-step, L2-resident);
// 16B-slice XOR swizzle (slice ^= (n>>1)&3) applied to per-lane global source
// AND ds_read address (linear LDS dest, per m104/m173). LN computed in-block
// on the LDS-resident 16x512 fp32 tile; writes y directly. Replaces
// out_gemm(split-K=2) + ln_kernel and all outp/outp2 traffic (~24 MB).
// ---------------------------------------------------------------------------
__global__ __launch_bounds__(512)
void out_ln(const unsigned short* __restrict__ Op,
            const float* __restrict__ ml,
            const unsigned short* __restrict__ Wph,
            const unsigned short* __restrict__ Wpl,
            const float* __restrict__ bp,
            const float* __restrict__ x,
            const float* __restrict__ gamma,
            const float* __restrict__ beta,
            float* __restrict__ y)
{
    extern __shared__ __align__(16) unsigned char smo[];
    unsigned short* ldsBh = (unsigned short*)smo;             // [512][32] 32768 B
    unsigned short* ldsBl = (unsigned short*)(smo + 32768);   // 32768 B
    unsigned short (*Ah)[40] = (unsigned short(*)[40])(smo + 65536); // 1280 B
    unsigned short (*Al)[40] = (unsigned short(*)[40])(smo + 66816); // 1280 B
    float (*Cf)[516] = (float(*)[516])smo;                    // 33,024 B (reuse)

    const int tid = threadIdx.x;
    const int m0 = blockIdx.x * 16;
    const int wave = tid >> 6, lane = tid & 63;
    const int lm = lane & 15, quad = lane >> 4;
    const int wn = wave * 64;             // this wave's n-range [wn, wn+64)

    // ---- A-staging thread roles (tid<64 active; indices safe for all) ----
    const int am  = (tid & 63) >> 2;      // 0..15 row within tile
    const int aks = (tid & 3) * 8;        // k-slice within 32
    const int m_row = m0 + am;
    const int b_row = m_row >> 11, s_row = m_row & 2047;
    const int qtA = s_row >> 6, qq = s_row & 63;

    // per-head combine scales c0/c1 for row m_row
    float c0[8], c1[8];
    #pragma unroll
    for (int h = 0; h < 8; ++h) {
        const size_t base0 = (((size_t)(b_row * 8 + h) * 32 + qtA) * 64 + qq) * 2;
        const size_t base1 = base0 + (size_t)512 * 64 * 2;
        const float m0_ = ml[base0], l0_ = ml[base0 + 1];
        const float m1_ = ml[base1], l1_ = ml[base1 + 1];
        const float mn = fmaxf(m0_, m1_);
        const float a0 = __expf(m0_ - mn), a1 = __expf(m1_ - mn);
        const float inv = 1.f / (a0 * l0_ + a1 * l1_);
        c0[h] = a0 * inv;
        c1[h] = a1 * inv;
    }

    // ---- B-staging geometry: chunk = 16 n-rows x 32 k (1024 B per plane) ---
    // wave w stages chunks [w*4, w*4+4) of both planes; lane covers row
    // ch*16 + (lane>>2), slice (lane&3). Source slice XOR-swizzled.
    const int brow_in_ch = lane >> 2;     // 0..15
    const int bslice     = lane & 3;      // 0..3

    f32x4 acc[4];
    #pragma unroll
    for (int j = 0; j < 4; ++j) acc[j] = (f32x4){0.f, 0.f, 0.f, 0.f};

    for (int k0 = 0; k0 < En; k0 += 32) {
        // B planes: async global->LDS, swizzled source
        #pragma unroll
        for (int i = 0; i < 4; ++i) {
            const int ch = wave * 4 + i;              // 0..31
            const int n = ch * 16 + brow_in_ch;
            const int sl = bslice ^ ((n >> 1) & 3);
            g2l16(Wph + (size_t)n * En + k0 + sl * 8, ldsBh + ch * 512);
            g2l16(Wpl + (size_t)n * En + k0 + sl * 8, ldsBl + ch * 512);
        }
        // A tile: combine + split (64 threads)
        if (tid < 64) {
            const int e0 = k0 + aks;
            const int hh = 7 - (e0 >> 6);
            const int dd = e0 & 63;
            const size_t p0 = (((size_t)((b_row * 8 + hh) * 32 + qtA)) * 64 + qq) * 64 + dd;
            bf8 o0 = *(const bf8*)(Op + p0);
            bf8 o1 = *(const bf8*)(Op + p0 + (size_t)512 * 64 * 64);
            const float w0 = c0[hh], w1 = c1[hh];
            unsigned short hi[8], lo[8];
            #pragma unroll
            for (int j = 0; j < 8; ++j) {
                const float v = w0 * bf2f((unsigned short)o0[j]) +
                                w1 * bf2f((unsigned short)o1[j]);
                split2(v, hi[j], lo[j]);
            }
            *(bf8*)&Ah[am][aks] = *(bf8*)&hi[0];
            *(bf8*)&Al[am][aks] = *(bf8*)&lo[0];
        }
        __syncthreads();                  // drains vmcnt (B) + lgkm (A)

        const bf8 a_h = *(const bf8*)&Ah[lm][quad * 8];
        const bf8 a_l = *(const bf8*)&Al[lm][quad * 8];
        #pragma unroll
        for (int ni = 0; ni < 4; ++ni) {
            const int n = wn + ni * 16 + lm;
            const int sq = (quad ^ ((n >> 1) & 3)) * 8;
            const bf8 b_h = *(const bf8*)(ldsBh + n * 32 + sq);
            const bf8 b_l = *(const bf8*)(ldsBl + n * 32 + sq);
            acc[ni] = __builtin_amdgcn_mfma_f32_16x16x32_bf16(a_h, b_h, acc[ni], 0, 0, 0);
            acc[ni] = __builtin_amdgcn_mfma_f32_16x16x32_bf16(a_h, b_l, acc[ni], 0, 0, 0);
            acc[ni] = __builtin_amdgcn_mfma_f32_16x16x32_bf16(a_l, b_h, acc[ni], 0, 0, 0);
        }
        __syncthreads();
    }

    // ---- epilogue: Cf = acc + bias + residual; then in-block LayerNorm ----
    #pragma unroll
    for (int ni = 0; ni < 4; ++ni) {
        const int n = wn + ni * 16 + lm;
        const float bpn = bp[n];
        #pragma unroll
        for (int r = 0; r < 4; ++r) {
            const int mr = quad * 4 + r;
            Cf[mr][n] = acc[ni][r] + bpn + x[(size_t)(m0 + mr) * En + n];
        }
    }
    __syncthreads();

    const int rt = tid >> 5;              // 0..15 row
    const int tg = tid & 31;              // 16 elems per thread
    float v[16];
    #pragma unroll
    for (int j4 = 0; j4 < 4; ++j4)
        *(float4*)&v[j4 * 4] = *(const float4*)&Cf[rt][tg * 16 + j4 * 4];
    float sum = 0.f, sq = 0.f;
    #pragma unroll
    for (int j = 0; j < 16; ++j) { sum += v[j]; sq += v[j] * v[j]; }
    #pragma unroll
    for (int o = 1; o < 32; o <<= 1) {
        sum += __shfl_xor(sum, o);
        sq  += __shfl_xor(sq, o);
    }
    const float mu = sum * (1.f / 512.f);
    const float var = sq * (1.f / 512.f) - mu * mu;
    const float rs = rsqrtf(var + 1e-5f);

    const float* g = gamma + tg * 16;
    const float* be = beta + tg * 16;
    float o[16];
    #pragma unroll
    for (int j = 0; j < 16; ++j)
        o[j] = (v[j] - mu) * rs * g[j] + be[j];
    float* yr = y + (size_t)(m0 + rt) * En + tg * 16;
    #pragma unroll
    for (int j4 = 0; j4 < 4; ++j4)
        *(float4*)(yr + j4 * 4) = *(float4*)&o[j4 * 4];
}

// ---------------------------------------------------------------------------
extern "C" void kernel_launch(void* const* d_in, const int* in_sizes, int n_in,
                              void* d_out, int out_size, void* d_ws, size_t ws_size,
                              hipStream_t stream)
{
    const float* x     = (const float*)d_in[0];
    const float* Wq    = (const float*)d_in[1];
    const float* Wk    = (const float*)d_in[2];
    const float* Wv    = (const float*)d_in[3];
    const float* Wp    = (const float*)d_in[4];
    const float* bp    = (const float*)d_in[5];
    const float* gamma = (const float*)d_in[6];
    const float* beta  = (const float*)d_in[7];
    // d_in[8] = mask (int32 tril) — causal, applied analytically.

    float* ws   = (float*)d_ws;
    float* ml   = ws;                            // 131,072 floats
    unsigned short* bfb = (unsigned short*)(ws + 2 * XY);
    unsigned short* xh  = bfb;
    unsigned short* xl  = bfb + XY;
    unsigned short* Wth = bfb + 2 * XY;
    unsigned short* Wtl = Wth + WT;
    unsigned short* Wph = Wtl + WT;
    unsigned short* Wpl = Wph + WP;
    unsigned short* qh  = Wpl + WP;
    unsigned short* ql  = qh + PL;
    unsigned short* kh  = ql + PL;
    unsigned short* kl  = kh + PL;
    unsigned short* vT  = kl + PL;
    unsigned short* Op = xh;                     // reuse (dead after qkv_gemm)

    const int attn_lds = 18432 * 2 + 256;        // 37,120 B
    hipFuncSetAttribute((const void*)attn,
                        hipFuncAttributeMaxDynamicSharedMemorySize, attn_lds);
    const int out_lds = 68096;                   // 64 KB B + 2.5 KB A
    hipFuncSetAttribute((const void*)out_ln,
                        hipFuncAttributeMaxDynamicSharedMemorySize, out_lds);

    prep<<<dim3(1344), 256, 0, stream>>>(x, Wp, Wq, Wk, Wv,
                                         xh, xl, Wph, Wpl, Wth, Wtl);
    qkv_gemm<<<dim3(Mn / 128, 24), 256, 0, stream>>>(xh, xl, Wth, Wtl,
                                                     qh, ql, kh, kl, vT);
    attn<<<dim3(1024), 256, attn_lds, stream>>>(qh, ql, kh, kl, vT, Op, ml);
    out_ln<<<dim3(Mn / 16), 512, out_lds, stream>>>(Op, ml, Wph, Wpl,
                                                    bp, x, gamma, beta,
                                                    (float*)d_out);
}

// Round 4
// 173.941 us; speedup vs baseline: 1.0627x; 1.0627x over previous
//
#include <hip/hip_runtime.h>

// Problem constants
constexpr int Bn = 2;
constexpr int Sn = 2048;
constexpr int En = 512;
constexpr int Hn = 8;
constexpr int Dn = 64;
constexpr int Mn = Bn * Sn;              // 4096 rows

typedef short bf8 __attribute__((ext_vector_type(8)));
typedef float f32x4 __attribute__((ext_vector_type(4)));

// element counts (ushort units) for the bf16 workspace region
constexpr size_t XY = (size_t)Mn * En;          // 2,097,152  x planes
constexpr size_t WT = (size_t)3 * En * En;      //   786,432  Wqkv transposed planes
constexpr size_t WP = (size_t)En * En;          //   262,144  Wp planes
constexpr size_t PL = (size_t)Bn * Hn * Sn * Dn;// 2,097,152  q/k/v planes

__device__ __forceinline__ unsigned short f2bf(float f) {
    unsigned int u = __float_as_uint(f);
    unsigned int r = 0x7FFFu + ((u >> 16) & 1u);
    return (unsigned short)((u + r) >> 16);
}
__device__ __forceinline__ float bf2f(unsigned short u) {
    return __uint_as_float(((unsigned int)u) << 16);
}
__device__ __forceinline__ void split2(float f, unsigned short& hi, unsigned short& lo) {
    hi = f2bf(f);
    lo = f2bf(f - bf2f(hi));
}

// global -> LDS direct copy, 16 B per lane. LDS dest is wave-uniform base +
// lane*16 (HW behavior); global source is per-lane.
__device__ __forceinline__ void g2l16(const unsigned short* g, unsigned short* l) {
    typedef __attribute__((address_space(1))) const unsigned int gu32;
    typedef __attribute__((address_space(3))) unsigned int lu32;
    __builtin_amdgcn_global_load_lds((gu32*)(unsigned long long)g,
                                     (lu32*)(unsigned int)(unsigned long long)l,
                                     16, 0, 0);
}

// ---------------------------------------------------------------------------
// Prep (fused): blocks [0,1024) presplit x; [1024,1152) presplit Wp;
// [1152,1344) transpose+split Wq/Wk/Wv -> Wt[n][k]. (R9-exact)
// ---------------------------------------------------------------------------
__global__ __launch_bounds__(256)
void prep(const float* __restrict__ x, const float* __restrict__ Wp,
          const float* __restrict__ Wq, const float* __restrict__ Wk,
          const float* __restrict__ Wv,
          unsigned short* __restrict__ xh, unsigned short* __restrict__ xl,
          unsigned short* __restrict__ Wph, unsigned short* __restrict__ Wpl,
          unsigned short* __restrict__ Wth, unsigned short* __restrict__ Wtl)
{
    __shared__ float t[64][65];
    const int bid = blockIdx.x;
    const int tid = threadIdx.x;

    if (bid < 1152) {
        const float* src = (bid < 1024) ? x : Wp;
        unsigned short* hp = (bid < 1024) ? xh : Wph;
        unsigned short* lp = (bid < 1024) ? xl : Wpl;
        const int blk = (bid < 1024) ? bid : (bid - 1024);
        const size_t base = ((size_t)blk * 256 + tid) * 8;
        float a[8];
        *(float4*)&a[0] = *(const float4*)(src + base);
        *(float4*)&a[4] = *(const float4*)(src + base + 4);
        unsigned short h[8], l[8];
        #pragma unroll
        for (int j = 0; j < 8; ++j) split2(a[j], h[j], l[j]);
        *(bf8*)(hp + base) = *(bf8*)&h[0];
        *(bf8*)(lp + base) = *(bf8*)&l[0];
        return;
    }

    const int idx = bid - 1152;           // 0..191
    const int ph = idx >> 3;              // 0..23
    const int proj = ph >> 3, h = ph & 7;
    const int e0 = (idx & 7) * 64;
    const float* W = (proj == 0) ? Wq : (proj == 1) ? Wk : Wv;
    const float* src = W + (size_t)h * En * Dn + (size_t)e0 * Dn;

    const int er = tid >> 2, cg = (tid & 3) * 16;
    #pragma unroll
    for (int c = 0; c < 4; ++c) {
        float4 v = *(const float4*)(src + (size_t)er * Dn + cg + 4 * c);
        t[er][cg + 4 * c + 0] = v.x;
        t[er][cg + 4 * c + 1] = v.y;
        t[er][cg + 4 * c + 2] = v.z;
        t[er][cg + 4 * c + 3] = v.w;
    }
    __syncthreads();

    const int d = tid >> 2, jg = (tid & 3) * 16;
    unsigned short h16[16], l16[16];
    #pragma unroll
    for (int j = 0; j < 16; ++j) split2(t[jg + j][d], h16[j], l16[j]);
    const size_t n = (size_t)proj * 512 + h * 64 + d;
    unsigned short* dh = Wth + n * En + e0 + jg;
    unsigned short* dl = Wtl + n * En + e0 + jg;
    *(bf8*)dh       = *(bf8*)&h16[0];
    *(bf8*)(dh + 8) = *(bf8*)&h16[8];
    *(bf8*)dl       = *(bf8*)&l16[0];
    *(bf8*)(dl + 8) = *(bf8*)&l16[8];
}

// ---------------------------------------------------------------------------
// Kernel 1 (R11-exact): fused QKV projection, 128x64 tiles, global_load_lds
// width-16 staging into linear LDS tiles. Grid (32,24)=768 -> 3/CU.
// ---------------------------------------------------------------------------
__global__ __launch_bounds__(256)
void qkv_gemm(const unsigned short* __restrict__ xh,
              const unsigned short* __restrict__ xl,
              const unsigned short* __restrict__ Wth,
              const unsigned short* __restrict__ Wtl,
              unsigned short* __restrict__ qh_g,
              unsigned short* __restrict__ ql_g,
              unsigned short* __restrict__ kh_g,
              unsigned short* __restrict__ kl_g,
              unsigned short* __restrict__ vT_g)
{
    __shared__ __align__(16) unsigned char smraw[24576];
    unsigned short* ldsAh = (unsigned short*)smraw;          // [128][32]
    unsigned short* ldsAl = ldsAh + 4096;
    unsigned short* ldsBh = ldsAl + 4096;                    // [64][32]
    unsigned short* ldsBl = ldsBh + 2048;
    float (*Cf)[68] = (float(*)[68])(smraw);   // 64 x 68 fp32 (epilogue)

    const int tid = threadIdx.x;
    const int m0 = blockIdx.x * 128;
    const int ny = blockIdx.y;            // 0..23
    const int proj = ny >> 3, h = ny & 7;

    const int wave = tid >> 6, lane = tid & 63;
    const int wm = (wave >> 1) * 64, wn = (wave & 1) * 32;
    const int lm = lane & 15, quad = lane >> 4;

    const int l4r = lane >> 2;            // 0..15
    const int l4c = (lane & 3) * 8;       // ushort col
    const unsigned short* gAh0 = xh + (size_t)(m0 + wave * 32 + l4r) * En + l4c;
    const unsigned short* gAh1 = gAh0 + (size_t)16 * En;
    const unsigned short* gAl0 = xl + (size_t)(m0 + wave * 32 + l4r) * En + l4c;
    const unsigned short* gAl1 = gAl0 + (size_t)16 * En;
    const unsigned short* gBh  = Wth + (size_t)(ny * 64 + wave * 16 + l4r) * En + l4c;
    const unsigned short* gBl  = Wtl + (size_t)(ny * 64 + wave * 16 + l4r) * En + l4c;
    unsigned short* dAh0 = ldsAh + wave * 1024;
    unsigned short* dAh1 = dAh0 + 512;
    unsigned short* dAl0 = ldsAl + wave * 1024;
    unsigned short* dAl1 = dAl0 + 512;
    unsigned short* dBh  = ldsBh + wave * 512;
    unsigned short* dBl  = ldsBl + wave * 512;

    f32x4 acc[4][2];
    #pragma unroll
    for (int i = 0; i < 4; ++i)
        #pragma unroll
        for (int j = 0; j < 2; ++j) acc[i][j] = (f32x4){0.f, 0.f, 0.f, 0.f};

    for (int k0 = 0; k0 < En; k0 += 32) {
        g2l16(gAh0 + k0, dAh0);
        g2l16(gAh1 + k0, dAh1);
        g2l16(gAl0 + k0, dAl0);
        g2l16(gAl1 + k0, dAl1);
        g2l16(gBh + k0, dBh);
        g2l16(gBl + k0, dBl);
        __syncthreads();

        bf8 a_h[4], a_l[4], b_h[2], b_l[2];
        #pragma unroll
        for (int mi = 0; mi < 4; ++mi) {
            a_h[mi] = *(const bf8*)(ldsAh + (wm + mi * 16 + lm) * 32 + quad * 8);
            a_l[mi] = *(const bf8*)(ldsAl + (wm + mi * 16 + lm) * 32 + quad * 8);
        }
        #pragma unroll
        for (int ni = 0; ni < 2; ++ni) {
            b_h[ni] = *(const bf8*)(ldsBh + (wn + ni * 16 + lm) * 32 + quad * 8);
            b_l[ni] = *(const bf8*)(ldsBl + (wn + ni * 16 + lm) * 32 + quad * 8);
        }
        #pragma unroll
        for (int mi = 0; mi < 4; ++mi)
            #pragma unroll
            for (int ni = 0; ni < 2; ++ni) {
                acc[mi][ni] = __builtin_amdgcn_mfma_f32_16x16x32_bf16(a_h[mi], b_h[ni], acc[mi][ni], 0, 0, 0);
                acc[mi][ni] = __builtin_amdgcn_mfma_f32_16x16x32_bf16(a_h[mi], b_l[ni], acc[mi][ni], 0, 0, 0);
                acc[mi][ni] = __builtin_amdgcn_mfma_f32_16x16x32_bf16(a_l[mi], b_h[ni], acc[mi][ni], 0, 0, 0);
            }
        __syncthreads();
    }

    if (proj < 2) {
        unsigned short* hp = (proj == 0) ? qh_g : kh_g;
        unsigned short* lp = (proj == 0) ? ql_g : kl_g;
        #pragma unroll
        for (int p = 0; p < 2; ++p) {
            if ((wave >> 1) == p) {
                #pragma unroll
                for (int mi = 0; mi < 4; ++mi)
                    #pragma unroll
                    for (int ni = 0; ni < 2; ++ni)
                        #pragma unroll
                        for (int r = 0; r < 4; ++r)
                            Cf[mi * 16 + quad * 4 + r][wn + ni * 16 + lm] = acc[mi][ni][r];
            }
            __syncthreads();
            {
                const int lr = tid & 63;
                const int cg = (tid >> 6) * 16;   // wave-uniform d-chunk
                const int m = m0 + p * 64 + lr;
                const int b = m >> 11, s = m & 2047;
                unsigned short hi[16], lo[16];
                #pragma unroll
                for (int j4 = 0; j4 < 4; ++j4) {
                    float4 v = *(const float4*)&Cf[lr][cg + 4 * j4];
                    split2(v.x, hi[4 * j4 + 0], lo[4 * j4 + 0]);
                    split2(v.y, hi[4 * j4 + 1], lo[4 * j4 + 1]);
                    split2(v.z, hi[4 * j4 + 2], lo[4 * j4 + 2]);
                    split2(v.w, hi[4 * j4 + 3], lo[4 * j4 + 3]);
                }
                const size_t base = (((size_t)(b * Hn + h) * Sn + s) * Dn) + cg;
                *(bf8*)(hp + base)     = *(bf8*)&hi[0];
                *(bf8*)(hp + base + 8) = *(bf8*)&hi[8];
                *(bf8*)(lp + base)     = *(bf8*)&lo[0];
                *(bf8*)(lp + base + 8) = *(bf8*)&lo[8];
            }
            __syncthreads();
        }
    } else {
        #pragma unroll
        for (int mi = 0; mi < 4; ++mi) {
            const int s0 = m0 + wm + mi * 16 + quad * 4;
            const int b = s0 >> 11, s = s0 & 2047;
            #pragma unroll
            for (int ni = 0; ni < 2; ++ni) {
                const int d = wn + ni * 16 + lm;
                ushort4 pk;
                pk.x = f2bf(acc[mi][ni][0]);
                pk.y = f2bf(acc[mi][ni][1]);
                pk.z = f2bf(acc[mi][ni][2]);
                pk.w = f2bf(acc[mi][ni][3]);
                *(ushort4*)(vT_g + ((size_t)(b * Hn + h) * Dn + d) * Sn + s) = pk;
            }
        }
    }
}

// ---------------------------------------------------------------------------
// Kernel 2 (R13): MFMA flash attention, QBLK=128 (8 waves, 512 threads).
// Halves K/V LDS-staging traffic and barrier count per q-row vs QBLK=64
// (8448 -> 4352 block-iterations). pslot stays 64-row-granular via wave>>2,
// so Op/ml layout and out_gemm are unchanged. 2-way split-t, XCD-aware bh
// mapping, defer-max (THR=12), setprio, tree max, wave-uniform skip of
// fully-masked diagonal-overrun tiles. Grid 512 blocks (2/CU), LDS 46,592 B.
// ---------------------------------------------------------------------------
__global__ __launch_bounds__(512, 4)
void attn(const unsigned short* __restrict__ qh_g,
          const unsigned short* __restrict__ ql_g,
          const unsigned short* __restrict__ kh_g,
          const unsigned short* __restrict__ kl_g,
          const unsigned short* __restrict__ vT_g,
          unsigned short* __restrict__ Op,
          float* __restrict__ ml)
{
    extern __shared__ unsigned short sm[];
    unsigned short (*khs)[72] = (unsigned short(*)[72])(sm);          // [64][72] hi
    unsigned short (*kls)[72] = (unsigned short(*)[72])(sm + 4608);   // [64][72] lo
    unsigned short (*vTs)[72] = (unsigned short(*)[72])(sm + 9216);   // [64][72] d-major
    unsigned short (*pts)[72] = (unsigned short(*)[72])(sm + 13824);  // [128][72]
    float* alf = (float*)(sm + 23040);                                // [128]

    const int bidx = blockIdx.x;          // 0..511
    const int xcd = bidx & 7;
    const int g = bidx >> 3;              // 0..63
    const int bh = xcd * 2 + (g & 1);     // 2 bh per XCD
    const int rest = g >> 1;              // 0..31
    const int hf = rest >> 4;             // K-range half
    const int a_ = rest & 15;
    const int qt = hf ? (15 - a_) : a_;   // 0..15, direction-alternated
    const int its = hf ? (qt + 1) : 0;
    const int ite = hf ? (2 * qt + 2) : (qt + 1);

    const int tid = threadIdx.x;
    const int wave = tid >> 6, lane = tid & 63;
    const int quad = lane >> 4, lq = lane & 15;
    const int wq = wave >> 2;             // 64-row subgroup (0/1)
    const int w4 = wave & 3;              // wave within subgroup
    const int qt64 = 2 * qt + wq;         // global 64-row q-tile index
    const int pslot = hf * 512 + bh * 32 + qt64;
    const int dt = qt64;                  // this wave's diagonal t-tile

    const unsigned short* khb = kh_g + (size_t)bh * Sn * Dn;
    const unsigned short* klb = kl_g + (size_t)bh * Sn * Dn;
    const unsigned short* vTb = vT_g + (size_t)bh * Dn * Sn;

    bf8 qfh[2], qfl[2];
    {
        const size_t qoff = ((size_t)bh * Sn + (size_t)qt * 128 + wave * 16 + lq) * Dn;
        #pragma unroll
        for (int c = 0; c < 2; ++c) {
            qfh[c] = *(const bf8*)(qh_g + qoff + c * 32 + quad * 8);
            qfl[c] = *(const bf8*)(ql_g + qoff + c * 32 + quad * 8);
        }
    }

    f32x4 accO[4];
    #pragma unroll
    for (int nj = 0; nj < 4; ++nj) accO[nj] = (f32x4){0.f, 0.f, 0.f, 0.f};
    float m = -1e30f, l = 0.f;

    // staging roles: 512 threads x 8 ushorts per plane covers [64][64]
    const int srow = tid & 63;
    const int sdg  = tid >> 6;            // 0..7, d/t slice of 8

    bf8 pk0, pl0, pv0;
    {
        const int t0 = its * 64;
        pk0 = *(const bf8*)(khb + (size_t)(t0 + srow) * Dn + sdg * 8);
        pl0 = *(const bf8*)(klb + (size_t)(t0 + srow) * Dn + sdg * 8);
        pv0 = *(const bf8*)(vTb + (size_t)srow * Sn + t0 + sdg * 8);
    }

    for (int it = its; it < ite; ++it) {
        __syncthreads();
        *(bf8*)&khs[srow][sdg * 8] = pk0;
        *(bf8*)&kls[srow][sdg * 8] = pl0;
        *(bf8*)&vTs[srow][sdg * 8] = pv0;
        __syncthreads();

        if (it + 1 < ite) {
            const int t1 = (it + 1) * 64;
            pk0 = *(const bf8*)(khb + (size_t)(t1 + srow) * Dn + sdg * 8);
            pl0 = *(const bf8*)(klb + (size_t)(t1 + srow) * Dn + sdg * 8);
            pv0 = *(const bf8*)(vTb + (size_t)srow * Sn + t1 + sdg * 8);
        }

        if (it > dt) continue;            // fully-masked tile for this wave

        f32x4 accS[4];
        #pragma unroll
        for (int mi = 0; mi < 4; ++mi) accS[mi] = (f32x4){0.f, 0.f, 0.f, 0.f};
        __builtin_amdgcn_s_setprio(1);
        #pragma unroll
        for (int mi = 0; mi < 4; ++mi) {
            #pragma unroll
            for (int c = 0; c < 2; ++c) {
                bf8 ah = *(const bf8*)&khs[mi * 16 + lq][c * 32 + quad * 8];
                bf8 al = *(const bf8*)&kls[mi * 16 + lq][c * 32 + quad * 8];
                accS[mi] = __builtin_amdgcn_mfma_f32_16x16x32_bf16(ah, qfh[c], accS[mi], 0, 0, 0);
                accS[mi] = __builtin_amdgcn_mfma_f32_16x16x32_bf16(ah, qfl[c], accS[mi], 0, 0, 0);
                accS[mi] = __builtin_amdgcn_mfma_f32_16x16x32_bf16(al, qfh[c], accS[mi], 0, 0, 0);
            }
        }
        __builtin_amdgcn_s_setprio(0);

        if (it == dt) {
            const int qrel = w4 * 16 + lq;    // q within this 64-row subgroup
            #pragma unroll
            for (int mi = 0; mi < 4; ++mi)
                #pragma unroll
                for (int r = 0; r < 4; ++r)
                    if (mi * 16 + quad * 4 + r > qrel) accS[mi][r] = -INFINITY;
        }

        float mt;
        {
            float t0 = fmaxf(fmaxf(accS[0][0], accS[0][1]), fmaxf(accS[0][2], accS[0][3]));
            float t1 = fmaxf(fmaxf(accS[1][0], accS[1][1]), fmaxf(accS[1][2], accS[1][3]));
            float t2 = fmaxf(fmaxf(accS[2][0], accS[2][1]), fmaxf(accS[2][2], accS[2][3]));
            float t3 = fmaxf(fmaxf(accS[3][0], accS[3][1]), fmaxf(accS[3][2], accS[3][3]));
            mt = fmaxf(fmaxf(t0, t1), fmaxf(t2, t3));
        }
        mt = fmaxf(mt, __shfl_xor(mt, 16));
        mt = fmaxf(mt, __shfl_xor(mt, 32));

        const bool defer = __all(mt <= m + 12.f);
        float mref, alpha = 1.f;
        if (defer) {
            mref = m;
        } else {
            mref = fmaxf(m, mt);
            alpha = __expf(m - mref);
        }

        float ls = 0.f;
        #pragma unroll
        for (int mi = 0; mi < 4; ++mi)
            #pragma unroll
            for (int r = 0; r < 4; ++r) {
                const float p = __expf(accS[mi][r] - mref);
                accS[mi][r] = p;
                ls += p;
            }
        ls += __shfl_xor(ls, 16);
        ls += __shfl_xor(ls, 32);
        if (defer) {
            l += ls;
        } else {
            l = l * alpha + ls;
            m = mref;
        }

        #pragma unroll
        for (int mi = 0; mi < 4; ++mi) {
            ushort4 pk;
            pk.x = f2bf(accS[mi][0]);
            pk.y = f2bf(accS[mi][1]);
            pk.z = f2bf(accS[mi][2]);
            pk.w = f2bf(accS[mi][3]);
            *(ushort4*)&pts[wave * 16 + lq][mi * 16 + quad * 4] = pk;
        }

        if (!defer) {
            if (quad == 0) alf[wave * 16 + lq] = alpha;
            float4 al4 = *(const float4*)&alf[wave * 16 + quad * 4];
            #pragma unroll
            for (int nj = 0; nj < 4; ++nj) {
                accO[nj][0] *= al4.x;
                accO[nj][1] *= al4.y;
                accO[nj][2] *= al4.z;
                accO[nj][3] *= al4.w;
            }
        }

        __builtin_amdgcn_s_setprio(1);
        #pragma unroll
        for (int c = 0; c < 2; ++c) {
            bf8 pf = *(const bf8*)&pts[wave * 16 + lq][c * 32 + quad * 8];
            #pragma unroll
            for (int nj = 0; nj < 4; ++nj) {
                bf8 vf = *(const bf8*)&vTs[nj * 16 + lq][c * 32 + quad * 8];
                accO[nj] = __builtin_amdgcn_mfma_f32_16x16x32_bf16(pf, vf, accO[nj], 0, 0, 0);
            }
        }
        __builtin_amdgcn_s_setprio(0);
    }

    if (quad == 0) {
        const size_t mi_ = ((size_t)pslot * 64 + w4 * 16 + lq) * 2;
        ml[mi_]     = m;
        ml[mi_ + 1] = l;
    }
    #pragma unroll
    for (int r = 0; r < 4; ++r) {
        const int q = w4 * 16 + quad * 4 + r;
        unsigned short* dst = Op + ((size_t)pslot * 64 + q) * 64;
        #pragma unroll
        for (int nj = 0; nj < 4; ++nj)
            dst[nj * 16 + lq] = f2bf(accO[nj][r]);
    }
}

// ---------------------------------------------------------------------------
// Kernel 3 (R11-exact): fused combine + out-projection + residual, split-K=2.
// B planes via global_load_lds into linear [128][32] LDS; A reg-staged with
// next-step prefetch. Grid (64, 4, 2) = 512 blocks (2/CU).
// ---------------------------------------------------------------------------
__global__ __launch_bounds__(256)
void out_gemm(const unsigned short* __restrict__ Op,
              const float* __restrict__ ml,
              const unsigned short* __restrict__ Wph,
              const unsigned short* __restrict__ Wpl,
              const float* __restrict__ bp,
              const float* __restrict__ x,
              float* __restrict__ outp,
              float* __restrict__ outp2)
{
    __shared__ unsigned short Ah[64][40], Al[64][40];
    __shared__ __align__(16) unsigned short Bh[128][32], Bl[128][32];

    const int tid = threadIdx.x;
    const int m0 = blockIdx.x * 64;
    const int n0 = blockIdx.y * 128;
    const int kz = blockIdx.z;
    const int kbeg = kz * 256, kend = kbeg + 256;

    const int wave = tid >> 6, lane = tid & 63;
    const int wm = (wave >> 1) * 32, wn = (wave & 1) * 64;
    const int lm = lane & 15, quad = lane >> 4;

    const int am = tid >> 2;
    const int aks = (tid & 3) * 8;
    const int m_row = m0 + am;
    const int b_row = m_row >> 11, s_row = m_row & 2047;
    const int qt = s_row >> 6, qq = s_row & 63;

    float c0[8], c1[8];
    #pragma unroll
    for (int h = 0; h < 8; ++h) {
        const size_t base0 = (((size_t)(b_row * 8 + h) * 32 + qt) * 64 + qq) * 2;
        const size_t base1 = base0 + (size_t)512 * 64 * 2;
        const float m0_ = ml[base0], l0_ = ml[base0 + 1];
        const float m1_ = ml[base1], l1_ = ml[base1 + 1];
        const float mn = fmaxf(m0_, m1_);
        const float a0 = __expf(m0_ - mn), a1 = __expf(m1_ - mn);
        const float inv = 1.f / (a0 * l0_ + a1 * l1_);
        c0[h] = a0 * inv;
        c1[h] = a1 * inv;
    }

    const int l4r = lane >> 2;
    const int l4c = (lane & 3) * 8;
    const unsigned short* gB0h = Wph + (size_t)(n0 + wave * 32 + l4r) * En + l4c;
    const unsigned short* gB1h = gB0h + (size_t)16 * En;
    const unsigned short* gB0l = Wpl + (size_t)(n0 + wave * 32 + l4r) * En + l4c;
    const unsigned short* gB1l = gB0l + (size_t)16 * En;
    unsigned short* dB0h = &Bh[0][0] + wave * 1024;
    unsigned short* dB1h = dB0h + 512;
    unsigned short* dB0l = &Bl[0][0] + wave * 1024;
    unsigned short* dB1l = dB0l + 512;

    f32x4 acc[2][4];
    #pragma unroll
    for (int i = 0; i < 2; ++i)
        #pragma unroll
        for (int j = 0; j < 4; ++j) acc[i][j] = (f32x4){0.f, 0.f, 0.f, 0.f};

    bf8 po0, po1;
    {
        const int e0 = kbeg + aks;
        const int hh = 7 - (e0 >> 6);
        const int dd = e0 & 63;
        const size_t p0 = (((size_t)((b_row * 8 + hh) * 32 + qt)) * 64 + qq) * 64 + dd;
        po0 = *(const bf8*)(Op + p0);
        po1 = *(const bf8*)(Op + p0 + (size_t)512 * 64 * 64);
    }

    for (int k0 = kbeg; k0 < kend; k0 += 32) {
        g2l16(gB0h + k0, dB0h);
        g2l16(gB1h + k0, dB1h);
        g2l16(gB0l + k0, dB0l);
        g2l16(gB1l + k0, dB1l);
        {
            const int h_cur = 7 - ((k0 + aks) >> 6);
            const float w0 = c0[h_cur], w1 = c1[h_cur];
            unsigned short hi[8], lo[8];
            #pragma unroll
            for (int j = 0; j < 8; ++j) {
                const float v = w0 * bf2f((unsigned short)po0[j]) +
                                w1 * bf2f((unsigned short)po1[j]);
                split2(v, hi[j], lo[j]);
            }
            *(bf8*)&Ah[am][aks] = *(bf8*)&hi[0];
            *(bf8*)&Al[am][aks] = *(bf8*)&lo[0];
        }
        __syncthreads();

        if (k0 + 32 < kend) {
            const int e0 = k0 + 32 + aks;
            const int hh = 7 - (e0 >> 6);
            const int dd = e0 & 63;
            const size_t p0 = (((size_t)((b_row * 8 + hh) * 32 + qt)) * 64 + qq) * 64 + dd;
            po0 = *(const bf8*)(Op + p0);
            po1 = *(const bf8*)(Op + p0 + (size_t)512 * 64 * 64);
        }

        bf8 a_h[2], a_l[2], b_h[4], b_l[4];
        #pragma unroll
        for (int mi = 0; mi < 2; ++mi) {
            a_h[mi] = *(const bf8*)&Ah[wm + mi * 16 + lm][quad * 8];
            a_l[mi] = *(const bf8*)&Al[wm + mi * 16 + lm][quad * 8];
        }
        #pragma unroll
        for (int ni = 0; ni < 4; ++ni) {
            b_h[ni] = *(const bf8*)&Bh[wn + ni * 16 + lm][quad * 8];
            b_l[ni] = *(const bf8*)&Bl[wn + ni * 16 + lm][quad * 8];
        }
        #pragma unroll
        for (int mi = 0; mi < 2; ++mi)
            #pragma unroll
            for (int ni = 0; ni < 4; ++ni) {
                acc[mi][ni] = __builtin_amdgcn_mfma_f32_16x16x32_bf16(a_h[mi], b_h[ni], acc[mi][ni], 0, 0, 0);
                acc[mi][ni] = __builtin_amdgcn_mfma_f32_16x16x32_bf16(a_h[mi], b_l[ni], acc[mi][ni], 0, 0, 0);
                acc[mi][ni] = __builtin_amdgcn_mfma_f32_16x16x32_bf16(a_l[mi], b_h[ni], acc[mi][ni], 0, 0, 0);
            }
        __syncthreads();
    }

    float* dst = kz ? outp2 : outp;
    #pragma unroll
    for (int mi = 0; mi < 2; ++mi) {
        #pragma unroll
        for (int r = 0; r < 4; ++r) {
            const int m = m0 + wm + mi * 16 + quad * 4 + r;
            #pragma unroll
            for (int ni = 0; ni < 4; ++ni) {
                const int n = n0 + wn + ni * 16 + lm;
                const size_t idx = (size_t)m * En + n;
                const float extra = kz ? 0.f : (bp[n] + x[idx]);
                dst[idx] = acc[mi][ni][r] + extra;
            }
        }
    }
}

// ---------------------------------------------------------------------------
// Kernel 4 (R9-exact): LayerNorm over (outp + outp2), 1 wave per row.
// ---------------------------------------------------------------------------
__global__ __launch_bounds__(256)
void ln_kernel(const float* __restrict__ outp,
               const float* __restrict__ outp2,
               const float* __restrict__ gamma,
               const float* __restrict__ beta,
               float* __restrict__ y)
{
    const int row = blockIdx.x * 4 + (threadIdx.x >> 6);
    const int lane = threadIdx.x & 63;
    const size_t off = (size_t)row * En + lane * 8;

    float a[8], b2[8];
    *(float4*)&a[0] = *(const float4*)(outp + off);
    *(float4*)&a[4] = *(const float4*)(outp + off + 4);
    *(float4*)&b2[0] = *(const float4*)(outp2 + off);
    *(float4*)&b2[4] = *(const float4*)(outp2 + off + 4);
    #pragma unroll
    for (int j = 0; j < 8; ++j) a[j] += b2[j];

    float sum = 0.f, sq = 0.f;
    #pragma unroll
    for (int j = 0; j < 8; ++j) { sum += a[j]; sq += a[j] * a[j]; }
    #pragma unroll
    for (int off_ = 1; off_ < 64; off_ <<= 1) {
        sum += __shfl_xor(sum, off_);
        sq  += __shfl_xor(sq, off_);
    }
    const float mu = sum * (1.f / 512.f);
    const float var = sq * (1.f / 512.f) - mu * mu;
    const float rs = rsqrtf(var + 1e-5f);

    const float* g = gamma + lane * 8;
    const float* be = beta + lane * 8;
    float o[8];
    #pragma unroll
    for (int j = 0; j < 8; ++j)
        o[j] = (a[j] - mu) * rs * g[j] + be[j];
    float* yr = y + off;
    *(float4*)(yr)     = *(float4*)&o[0];
    *(float4*)(yr + 4) = *(float4*)&o[4];
}

// ---------------------------------------------------------------------------
extern "C" void kernel_launch(void* const* d_in, const int* in_sizes, int n_in,
                              void* d_out, int out_size, void* d_ws, size_t ws_size,
                              hipStream_t stream)
{
    const float* x     = (const float*)d_in[0];
    const float* Wq    = (const float*)d_in[1];
    const float* Wk    = (const float*)d_in[2];
    const float* Wv    = (const float*)d_in[3];
    const float* Wp    = (const float*)d_in[4];
    const float* bp    = (const float*)d_in[5];
    const float* gamma = (const float*)d_in[6];
    const float* beta  = (const float*)d_in[7];
    // d_in[8] = mask (int32 tril) — causal, applied analytically.

    float* ws   = (float*)d_ws;
    float* ml   = ws;                            // 131,072 floats
    float* outp = ws + XY;                       // 2M floats (8 MB)
    unsigned short* bfb = (unsigned short*)(ws + 2 * XY);
    unsigned short* xh  = bfb;
    unsigned short* xl  = bfb + XY;
    unsigned short* Wth = bfb + 2 * XY;
    unsigned short* Wtl = Wth + WT;
    unsigned short* Wph = Wtl + WT;
    unsigned short* Wpl = Wph + WP;
    unsigned short* qh  = Wpl + WP;
    unsigned short* ql  = qh + PL;
    unsigned short* kh  = ql + PL;
    unsigned short* kl  = kh + PL;
    unsigned short* vT  = kl + PL;
    unsigned short* Op = xh;                     // reuse (dead after qkv_gemm)
    float* outp2 = (float*)qh;                   // reuse (dead after attn)

    const int attn_lds = 46592;                  // 3x9216 + 18432 + 512
    hipFuncSetAttribute((const void*)attn,
                        hipFuncAttributeMaxDynamicSharedMemorySize, attn_lds);

    prep<<<dim3(1344), 256, 0, stream>>>(x, Wp, Wq, Wk, Wv,
                                         xh, xl, Wph, Wpl, Wth, Wtl);
    qkv_gemm<<<dim3(Mn / 128, 24), 256, 0, stream>>>(xh, xl, Wth, Wtl,
                                                     qh, ql, kh, kl, vT);
    attn<<<dim3(512), 512, attn_lds, stream>>>(qh, ql, kh, kl, vT, Op, ml);
    out_gemm<<<dim3(Mn / 64, En / 128, 2), 256, 0, stream>>>(Op, ml, Wph, Wpl,
                                                             bp, x, outp, outp2);
    ln_kernel<<<dim3(Mn / 4), 256, 0, stream>>>(outp, outp2, gamma, beta,
                                                (float*)d_out);
}

// Round 5
// 172.215 us; speedup vs baseline: 1.0733x; 1.0100x over previous
//
#include <hip/hip_runtime.h>

// Problem constants
constexpr int Bn = 2;
constexpr int Sn = 2048;
constexpr int En = 512;
constexpr int Hn = 8;
constexpr int Dn = 64;
constexpr int Mn = Bn * Sn;              // 4096 rows

typedef short bf8 __attribute__((ext_vector_type(8)));
typedef float f32x4 __attribute__((ext_vector_type(4)));

// element counts (ushort units) for the bf16 workspace region
constexpr size_t XY = (size_t)Mn * En;          // 2,097,152  x planes
constexpr size_t WT = (size_t)3 * En * En;      //   786,432  Wqkv transposed planes
constexpr size_t WP = (size_t)En * En;          //   262,144  Wp planes
constexpr size_t PL = (size_t)Bn * Hn * Sn * Dn;// 2,097,152  q/k/v planes

__device__ __forceinline__ unsigned short f2bf(float f) {
    unsigned int u = __float_as_uint(f);
    unsigned int r = 0x7FFFu + ((u >> 16) & 1u);
    return (unsigned short)((u + r) >> 16);
}
__device__ __forceinline__ float bf2f(unsigned short u) {
    return __uint_as_float(((unsigned int)u) << 16);
}
__device__ __forceinline__ void split2(float f, unsigned short& hi, unsigned short& lo) {
    hi = f2bf(f);
    lo = f2bf(f - bf2f(hi));
}

// global -> LDS direct copy, 16 B per lane. LDS dest is wave-uniform base +
// lane*16 (HW behavior); global source is per-lane.
__device__ __forceinline__ void g2l16(const unsigned short* g, unsigned short* l) {
    typedef __attribute__((address_space(1))) const unsigned int gu32;
    typedef __attribute__((address_space(3))) unsigned int lu32;
    __builtin_amdgcn_global_load_lds((gu32*)(unsigned long long)g,
                                     (lu32*)(unsigned int)(unsigned long long)l,
                                     16, 0, 0);
}

// ---------------------------------------------------------------------------
// Prep (fused): blocks [0,1024) presplit x; [1024,1152) presplit Wp;
// [1152,1344) transpose+split Wq/Wk/Wv -> Wt[n][k]. (R9-exact)
// ---------------------------------------------------------------------------
__global__ __launch_bounds__(256)
void prep(const float* __restrict__ x, const float* __restrict__ Wp,
          const float* __restrict__ Wq, const float* __restrict__ Wk,
          const float* __restrict__ Wv,
          unsigned short* __restrict__ xh, unsigned short* __restrict__ xl,
          unsigned short* __restrict__ Wph, unsigned short* __restrict__ Wpl,
          unsigned short* __restrict__ Wth, unsigned short* __restrict__ Wtl)
{
    __shared__ float t[64][65];
    const int bid = blockIdx.x;
    const int tid = threadIdx.x;

    if (bid < 1152) {
        const float* src = (bid < 1024) ? x : Wp;
        unsigned short* hp = (bid < 1024) ? xh : Wph;
        unsigned short* lp = (bid < 1024) ? xl : Wpl;
        const int blk = (bid < 1024) ? bid : (bid - 1024);
        const size_t base = ((size_t)blk * 256 + tid) * 8;
        float a[8];
        *(float4*)&a[0] = *(const float4*)(src + base);
        *(float4*)&a[4] = *(const float4*)(src + base + 4);
        unsigned short h[8], l[8];
        #pragma unroll
        for (int j = 0; j < 8; ++j) split2(a[j], h[j], l[j]);
        *(bf8*)(hp + base) = *(bf8*)&h[0];
        *(bf8*)(lp + base) = *(bf8*)&l[0];
        return;
    }

    const int idx = bid - 1152;           // 0..191
    const int ph = idx >> 3;              // 0..23
    const int proj = ph >> 3, h = ph & 7;
    const int e0 = (idx & 7) * 64;
    const float* W = (proj == 0) ? Wq : (proj == 1) ? Wk : Wv;
    const float* src = W + (size_t)h * En * Dn + (size_t)e0 * Dn;

    const int er = tid >> 2, cg = (tid & 3) * 16;
    #pragma unroll
    for (int c = 0; c < 4; ++c) {
        float4 v = *(const float4*)(src + (size_t)er * Dn + cg + 4 * c);
        t[er][cg + 4 * c + 0] = v.x;
        t[er][cg + 4 * c + 1] = v.y;
        t[er][cg + 4 * c + 2] = v.z;
        t[er][cg + 4 * c + 3] = v.w;
    }
    __syncthreads();

    const int d = tid >> 2, jg = (tid & 3) * 16;
    unsigned short h16[16], l16[16];
    #pragma unroll
    for (int j = 0; j < 16; ++j) split2(t[jg + j][d], h16[j], l16[j]);
    const size_t n = (size_t)proj * 512 + h * 64 + d;
    unsigned short* dh = Wth + n * En + e0 + jg;
    unsigned short* dl = Wtl + n * En + e0 + jg;
    *(bf8*)dh       = *(bf8*)&h16[0];
    *(bf8*)(dh + 8) = *(bf8*)&h16[8];
    *(bf8*)dl       = *(bf8*)&l16[0];
    *(bf8*)(dl + 8) = *(bf8*)&l16[8];
}

// ---------------------------------------------------------------------------
// Kernel 1 (R14): fused QKV projection, 128x64 tiles, DOUBLE-BUFFERED
// global_load_lds staging (T3 2-phase minimum): issue stage(t+1) before
// MFMA(t); one __syncthreads per K-step drains vmcnt(t+1)+lgkm(t).
// LDS 48 KB x 3 blocks/CU = 144 KB <= 160. Math identical to R11.
// ---------------------------------------------------------------------------
__global__ __launch_bounds__(256)
void qkv_gemm(const unsigned short* __restrict__ xh,
              const unsigned short* __restrict__ xl,
              const unsigned short* __restrict__ Wth,
              const unsigned short* __restrict__ Wtl,
              unsigned short* __restrict__ qh_g,
              unsigned short* __restrict__ ql_g,
              unsigned short* __restrict__ kh_g,
              unsigned short* __restrict__ kl_g,
              unsigned short* __restrict__ vT_g)
{
    __shared__ __align__(16) unsigned char smraw[49152];
    // dbuf layout (ushort units): Ah[2][4096] Al[2][4096] Bh[2][2048] Bl[2][2048]
    unsigned short* ldsAh = (unsigned short*)smraw;
    unsigned short* ldsAl = ldsAh + 8192;
    unsigned short* ldsBh = ldsAl + 8192;
    unsigned short* ldsBl = ldsBh + 4096;
    float (*Cf)[68] = (float(*)[68])(smraw);   // 64 x 68 fp32 (epilogue reuse)

    const int tid = threadIdx.x;
    const int m0 = blockIdx.x * 128;
    const int ny = blockIdx.y;            // 0..23
    const int proj = ny >> 3, h = ny & 7;

    const int wave = tid >> 6, lane = tid & 63;
    const int wm = (wave >> 1) * 64, wn = (wave & 1) * 32;
    const int lm = lane & 15, quad = lane >> 4;

    const int l4r = lane >> 2;            // 0..15
    const int l4c = (lane & 3) * 8;       // ushort col
    const unsigned short* gAh0 = xh + (size_t)(m0 + wave * 32 + l4r) * En + l4c;
    const unsigned short* gAh1 = gAh0 + (size_t)16 * En;
    const unsigned short* gAl0 = xl + (size_t)(m0 + wave * 32 + l4r) * En + l4c;
    const unsigned short* gAl1 = gAl0 + (size_t)16 * En;
    const unsigned short* gBh  = Wth + (size_t)(ny * 64 + wave * 16 + l4r) * En + l4c;
    const unsigned short* gBl  = Wtl + (size_t)(ny * 64 + wave * 16 + l4r) * En + l4c;
    const int offA = wave * 1024;         // chunk base within an A buffer
    const int offB = wave * 512;          // chunk base within a B buffer

    f32x4 acc[4][2];
    #pragma unroll
    for (int i = 0; i < 4; ++i)
        #pragma unroll
        for (int j = 0; j < 2; ++j) acc[i][j] = (f32x4){0.f, 0.f, 0.f, 0.f};

    // prologue: stage K-step 0 into buffer 0
    g2l16(gAh0, ldsAh + offA);
    g2l16(gAh1, ldsAh + offA + 512);
    g2l16(gAl0, ldsAl + offA);
    g2l16(gAl1, ldsAl + offA + 512);
    g2l16(gBh,  ldsBh + offB);
    g2l16(gBl,  ldsBl + offB);

    int cur = 0;
    for (int k0 = 0; k0 < En; k0 += 32) {
        __syncthreads();                  // drains stage(k0) + prior reads
        const int nxt = cur ^ 1;
        if (k0 + 32 < En) {               // issue stage(k0+32) -> buf nxt
            g2l16(gAh0 + k0 + 32, ldsAh + nxt * 4096 + offA);
            g2l16(gAh1 + k0 + 32, ldsAh + nxt * 4096 + offA + 512);
            g2l16(gAl0 + k0 + 32, ldsAl + nxt * 4096 + offA);
            g2l16(gAl1 + k0 + 32, ldsAl + nxt * 4096 + offA + 512);
            g2l16(gBh + k0 + 32,  ldsBh + nxt * 2048 + offB);
            g2l16(gBl + k0 + 32,  ldsBl + nxt * 2048 + offB);
        }

        const unsigned short* bAh = ldsAh + cur * 4096;
        const unsigned short* bAl = ldsAl + cur * 4096;
        const unsigned short* bBh = ldsBh + cur * 2048;
        const unsigned short* bBl = ldsBl + cur * 2048;
        bf8 a_h[4], a_l[4], b_h[2], b_l[2];
        #pragma unroll
        for (int mi = 0; mi < 4; ++mi) {
            a_h[mi] = *(const bf8*)(bAh + (wm + mi * 16 + lm) * 32 + quad * 8);
            a_l[mi] = *(const bf8*)(bAl + (wm + mi * 16 + lm) * 32 + quad * 8);
        }
        #pragma unroll
        for (int ni = 0; ni < 2; ++ni) {
            b_h[ni] = *(const bf8*)(bBh + (wn + ni * 16 + lm) * 32 + quad * 8);
            b_l[ni] = *(const bf8*)(bBl + (wn + ni * 16 + lm) * 32 + quad * 8);
        }
        #pragma unroll
        for (int mi = 0; mi < 4; ++mi)
            #pragma unroll
            for (int ni = 0; ni < 2; ++ni) {
                acc[mi][ni] = __builtin_amdgcn_mfma_f32_16x16x32_bf16(a_h[mi], b_h[ni], acc[mi][ni], 0, 0, 0);
                acc[mi][ni] = __builtin_amdgcn_mfma_f32_16x16x32_bf16(a_h[mi], b_l[ni], acc[mi][ni], 0, 0, 0);
                acc[mi][ni] = __builtin_amdgcn_mfma_f32_16x16x32_bf16(a_l[mi], b_h[ni], acc[mi][ni], 0, 0, 0);
            }
        cur = nxt;
    }
    __syncthreads();                      // all LDS reads done before Cf reuse

    if (proj < 2) {
        unsigned short* hp = (proj == 0) ? qh_g : kh_g;
        unsigned short* lp = (proj == 0) ? ql_g : kl_g;
        #pragma unroll
        for (int p = 0; p < 2; ++p) {
            if ((wave >> 1) == p) {
                #pragma unroll
                for (int mi = 0; mi < 4; ++mi)
                    #pragma unroll
                    for (int ni = 0; ni < 2; ++ni)
                        #pragma unroll
                        for (int r = 0; r < 4; ++r)
                            Cf[mi * 16 + quad * 4 + r][wn + ni * 16 + lm] = acc[mi][ni][r];
            }
            __syncthreads();
            {
                const int lr = tid & 63;
                const int cg = (tid >> 6) * 16;   // wave-uniform d-chunk
                const int m = m0 + p * 64 + lr;
                const int b = m >> 11, s = m & 2047;
                unsigned short hi[16], lo[16];
                #pragma unroll
                for (int j4 = 0; j4 < 4; ++j4) {
                    float4 v = *(const float4*)&Cf[lr][cg + 4 * j4];
                    split2(v.x, hi[4 * j4 + 0], lo[4 * j4 + 0]);
                    split2(v.y, hi[4 * j4 + 1], lo[4 * j4 + 1]);
                    split2(v.z, hi[4 * j4 + 2], lo[4 * j4 + 2]);
                    split2(v.w, hi[4 * j4 + 3], lo[4 * j4 + 3]);
                }
                const size_t base = (((size_t)(b * Hn + h) * Sn + s) * Dn) + cg;
                *(bf8*)(hp + base)     = *(bf8*)&hi[0];
                *(bf8*)(hp + base + 8) = *(bf8*)&hi[8];
                *(bf8*)(lp + base)     = *(bf8*)&lo[0];
                *(bf8*)(lp + base + 8) = *(bf8*)&lo[8];
            }
            __syncthreads();
        }
    } else {
        #pragma unroll
        for (int mi = 0; mi < 4; ++mi) {
            const int s0 = m0 + wm + mi * 16 + quad * 4;
            const int b = s0 >> 11, s = s0 & 2047;
            #pragma unroll
            for (int ni = 0; ni < 2; ++ni) {
                const int d = wn + ni * 16 + lm;
                ushort4 pk;
                pk.x = f2bf(acc[mi][ni][0]);
                pk.y = f2bf(acc[mi][ni][1]);
                pk.z = f2bf(acc[mi][ni][2]);
                pk.w = f2bf(acc[mi][ni][3]);
                *(ushort4*)(vT_g + ((size_t)(b * Hn + h) * Dn + d) * Sn + s) = pk;
            }
        }
    }
}

// ---------------------------------------------------------------------------
// Kernel 2 (R14): MFMA flash attention, QBLK=128, PAIRED work items for
// perfect balance: each block runs phase A = (qt, hf=0, t in [0,qt+1)) then
// phase B = (15-qt, hf=1, t in [qt'+1, 2qt'+2)) -> exactly 17 tiles/block.
// 256 uniform blocks (1/CU), zero tail imbalance. pslot/ml/Op layout and
// all arithmetic identical to R13; out_gemm combine unchanged.
// ---------------------------------------------------------------------------
__global__ __launch_bounds__(512, 4)
void attn(const unsigned short* __restrict__ qh_g,
          const unsigned short* __restrict__ ql_g,
          const unsigned short* __restrict__ kh_g,
          const unsigned short* __restrict__ kl_g,
          const unsigned short* __restrict__ vT_g,
          unsigned short* __restrict__ Op,
          float* __restrict__ ml)
{
    extern __shared__ unsigned short sm[];
    unsigned short (*khs)[72] = (unsigned short(*)[72])(sm);          // [64][72] hi
    unsigned short (*kls)[72] = (unsigned short(*)[72])(sm + 4608);   // [64][72] lo
    unsigned short (*vTs)[72] = (unsigned short(*)[72])(sm + 9216);   // [64][72] d-major
    unsigned short (*pts)[72] = (unsigned short(*)[72])(sm + 13824);  // [128][72]
    float* alf = (float*)(sm + 23040);                                // [128]

    const int bidx = blockIdx.x;          // 0..255
    const int xcd = bidx & 7;
    const int g = bidx >> 3;              // 0..31
    const int bh = xcd * 2 + (g & 1);     // 2 bh per XCD (K/V L2-local)
    const int qp = g >> 1;                // 0..15

    const int tid = threadIdx.x;
    const int wave = tid >> 6, lane = tid & 63;
    const int quad = lane >> 4, lq = lane & 15;
    const int wq = wave >> 2;             // 64-row subgroup (0/1)
    const int w4 = wave & 3;              // wave within subgroup

    const unsigned short* khb = kh_g + (size_t)bh * Sn * Dn;
    const unsigned short* klb = kl_g + (size_t)bh * Sn * Dn;
    const unsigned short* vTb = vT_g + (size_t)bh * Dn * Sn;

    const int srow = tid & 63;
    const int sdg  = tid >> 6;            // 0..7, 8-ushort slice

    #pragma unroll 1
    for (int ph = 0; ph < 2; ++ph) {
        const int qt  = ph ? (15 - qp) : qp;
        const int its = ph ? (qt + 1) : 0;
        const int ite = ph ? (2 * qt + 2) : (qt + 1);
        const int qt64 = 2 * qt + wq;     // global 64-row q-tile index
        const int pslot = ph * 512 + bh * 32 + qt64;
        const int dt = qt64;              // diagonal t-tile for this wave

        bf8 qfh[2], qfl[2];
        {
            const size_t qoff = ((size_t)bh * Sn + (size_t)qt * 128 + wave * 16 + lq) * Dn;
            #pragma unroll
            for (int c = 0; c < 2; ++c) {
                qfh[c] = *(const bf8*)(qh_g + qoff + c * 32 + quad * 8);
                qfl[c] = *(const bf8*)(ql_g + qoff + c * 32 + quad * 8);
            }
        }

        f32x4 accO[4];
        #pragma unroll
        for (int nj = 0; nj < 4; ++nj) accO[nj] = (f32x4){0.f, 0.f, 0.f, 0.f};
        float m = -1e30f, l = 0.f;

        bf8 pk0, pl0, pv0;
        {
            const int t0 = its * 64;
            pk0 = *(const bf8*)(khb + (size_t)(t0 + srow) * Dn + sdg * 8);
            pl0 = *(const bf8*)(klb + (size_t)(t0 + srow) * Dn + sdg * 8);
            pv0 = *(const bf8*)(vTb + (size_t)srow * Sn + t0 + sdg * 8);
        }

        for (int it = its; it < ite; ++it) {
            __syncthreads();
            *(bf8*)&khs[srow][sdg * 8] = pk0;
            *(bf8*)&kls[srow][sdg * 8] = pl0;
            *(bf8*)&vTs[srow][sdg * 8] = pv0;
            __syncthreads();

            if (it + 1 < ite) {
                const int t1 = (it + 1) * 64;
                pk0 = *(const bf8*)(khb + (size_t)(t1 + srow) * Dn + sdg * 8);
                pl0 = *(const bf8*)(klb + (size_t)(t1 + srow) * Dn + sdg * 8);
                pv0 = *(const bf8*)(vTb + (size_t)srow * Sn + t1 + sdg * 8);
            }

            if (it > dt) continue;        // fully-masked tile for this wave

            f32x4 accS[4];
            #pragma unroll
            for (int mi = 0; mi < 4; ++mi) accS[mi] = (f32x4){0.f, 0.f, 0.f, 0.f};
            __builtin_amdgcn_s_setprio(1);
            #pragma unroll
            for (int mi = 0; mi < 4; ++mi) {
                #pragma unroll
                for (int c = 0; c < 2; ++c) {
                    bf8 ah = *(const bf8*)&khs[mi * 16 + lq][c * 32 + quad * 8];
                    bf8 al = *(const bf8*)&kls[mi * 16 + lq][c * 32 + quad * 8];
                    accS[mi] = __builtin_amdgcn_mfma_f32_16x16x32_bf16(ah, qfh[c], accS[mi], 0, 0, 0);
                    accS[mi] = __builtin_amdgcn_mfma_f32_16x16x32_bf16(ah, qfl[c], accS[mi], 0, 0, 0);
                    accS[mi] = __builtin_amdgcn_mfma_f32_16x16x32_bf16(al, qfh[c], accS[mi], 0, 0, 0);
                }
            }
            __builtin_amdgcn_s_setprio(0);

            if (it == dt) {
                const int qrel = w4 * 16 + lq;    // q within 64-row subgroup
                #pragma unroll
                for (int mi = 0; mi < 4; ++mi)
                    #pragma unroll
                    for (int r = 0; r < 4; ++r)
                        if (mi * 16 + quad * 4 + r > qrel) accS[mi][r] = -INFINITY;
            }

            float mt;
            {
                float t0 = fmaxf(fmaxf(accS[0][0], accS[0][1]), fmaxf(accS[0][2], accS[0][3]));
                float t1 = fmaxf(fmaxf(accS[1][0], accS[1][1]), fmaxf(accS[1][2], accS[1][3]));
                float t2 = fmaxf(fmaxf(accS[2][0], accS[2][1]), fmaxf(accS[2][2], accS[2][3]));
                float t3 = fmaxf(fmaxf(accS[3][0], accS[3][1]), fmaxf(accS[3][2], accS[3][3]));
                mt = fmaxf(fmaxf(t0, t1), fmaxf(t2, t3));
            }
            mt = fmaxf(mt, __shfl_xor(mt, 16));
            mt = fmaxf(mt, __shfl_xor(mt, 32));

            const bool defer = __all(mt <= m + 12.f);
            float mref, alpha = 1.f;
            if (defer) {
                mref = m;
            } else {
                mref = fmaxf(m, mt);
                alpha = __expf(m - mref);
            }

            float ls = 0.f;
            #pragma unroll
            for (int mi = 0; mi < 4; ++mi)
                #pragma unroll
                for (int r = 0; r < 4; ++r) {
                    const float p = __expf(accS[mi][r] - mref);
                    accS[mi][r] = p;
                    ls += p;
                }
            ls += __shfl_xor(ls, 16);
            ls += __shfl_xor(ls, 32);
            if (defer) {
                l += ls;
            } else {
                l = l * alpha + ls;
                m = mref;
            }

            #pragma unroll
            for (int mi = 0; mi < 4; ++mi) {
                ushort4 pk;
                pk.x = f2bf(accS[mi][0]);
                pk.y = f2bf(accS[mi][1]);
                pk.z = f2bf(accS[mi][2]);
                pk.w = f2bf(accS[mi][3]);
                *(ushort4*)&pts[wave * 16 + lq][mi * 16 + quad * 4] = pk;
            }

            if (!defer) {
                if (quad == 0) alf[wave * 16 + lq] = alpha;
                float4 al4 = *(const float4*)&alf[wave * 16 + quad * 4];
                #pragma unroll
                for (int nj = 0; nj < 4; ++nj) {
                    accO[nj][0] *= al4.x;
                    accO[nj][1] *= al4.y;
                    accO[nj][2] *= al4.z;
                    accO[nj][3] *= al4.w;
                }
            }

            __builtin_amdgcn_s_setprio(1);
            #pragma unroll
            for (int c = 0; c < 2; ++c) {
                bf8 pf = *(const bf8*)&pts[wave * 16 + lq][c * 32 + quad * 8];
                #pragma unroll
                for (int nj = 0; nj < 4; ++nj) {
                    bf8 vf = *(const bf8*)&vTs[nj * 16 + lq][c * 32 + quad * 8];
                    accO[nj] = __builtin_amdgcn_mfma_f32_16x16x32_bf16(pf, vf, accO[nj], 0, 0, 0);
                }
            }
            __builtin_amdgcn_s_setprio(0);
        }

        if (quad == 0) {
            const size_t mi_ = ((size_t)pslot * 64 + w4 * 16 + lq) * 2;
            ml[mi_]     = m;
            ml[mi_ + 1] = l;
        }
        #pragma unroll
        for (int r = 0; r < 4; ++r) {
            const int q = w4 * 16 + quad * 4 + r;
            unsigned short* dst = Op + ((size_t)pslot * 64 + q) * 64;
            #pragma unroll
            for (int nj = 0; nj < 4; ++nj)
                dst[nj * 16 + lq] = f2bf(accO[nj][r]);
        }
    }
}

// ---------------------------------------------------------------------------
// Kernel 3 (R11-exact): fused combine + out-projection + residual, split-K=2.
// B planes via global_load_lds into linear [128][32] LDS; A reg-staged with
// next-step prefetch. Grid (64, 4, 2) = 512 blocks (2/CU).
// ---------------------------------------------------------------------------
__global__ __launch_bounds__(256)
void out_gemm(const unsigned short* __restrict__ Op,
              const float* __restrict__ ml,
              const unsigned short* __restrict__ Wph,
              const unsigned short* __restrict__ Wpl,
              const float* __restrict__ bp,
              const float* __restrict__ x,
              float* __restrict__ outp,
              float* __restrict__ outp2)
{
    __shared__ unsigned short Ah[64][40], Al[64][40];
    __shared__ __align__(16) unsigned short Bh[128][32], Bl[128][32];

    const int tid = threadIdx.x;
    const int m0 = blockIdx.x * 64;
    const int n0 = blockIdx.y * 128;
    const int kz = blockIdx.z;
    const int kbeg = kz * 256, kend = kbeg + 256;

    const int wave = tid >> 6, lane = tid & 63;
    const int wm = (wave >> 1) * 32, wn = (wave & 1) * 64;
    const int lm = lane & 15, quad = lane >> 4;

    const int am = tid >> 2;
    const int aks = (tid & 3) * 8;
    const int m_row = m0 + am;
    const int b_row = m_row >> 11, s_row = m_row & 2047;
    const int qt = s_row >> 6, qq = s_row & 63;

    float c0[8], c1[8];
    #pragma unroll
    for (int h = 0; h < 8; ++h) {
        const size_t base0 = (((size_t)(b_row * 8 + h) * 32 + qt) * 64 + qq) * 2;
        const size_t base1 = base0 + (size_t)512 * 64 * 2;
        const float m0_ = ml[base0], l0_ = ml[base0 + 1];
        const float m1_ = ml[base1], l1_ = ml[base1 + 1];
        const float mn = fmaxf(m0_, m1_);
        const float a0 = __expf(m0_ - mn), a1 = __expf(m1_ - mn);
        const float inv = 1.f / (a0 * l0_ + a1 * l1_);
        c0[h] = a0 * inv;
        c1[h] = a1 * inv;
    }

    const int l4r = lane >> 2;
    const int l4c = (lane & 3) * 8;
    const unsigned short* gB0h = Wph + (size_t)(n0 + wave * 32 + l4r) * En + l4c;
    const unsigned short* gB1h = gB0h + (size_t)16 * En;
    const unsigned short* gB0l = Wpl + (size_t)(n0 + wave * 32 + l4r) * En + l4c;
    const unsigned short* gB1l = gB0l + (size_t)16 * En;
    unsigned short* dB0h = &Bh[0][0] + wave * 1024;
    unsigned short* dB1h = dB0h + 512;
    unsigned short* dB0l = &Bl[0][0] + wave * 1024;
    unsigned short* dB1l = dB0l + 512;

    f32x4 acc[2][4];
    #pragma unroll
    for (int i = 0; i < 2; ++i)
        #pragma unroll
        for (int j = 0; j < 4; ++j) acc[i][j] = (f32x4){0.f, 0.f, 0.f, 0.f};

    bf8 po0, po1;
    {
        const int e0 = kbeg + aks;
        const int hh = 7 - (e0 >> 6);
        const int dd = e0 & 63;
        const size_t p0 = (((size_t)((b_row * 8 + hh) * 32 + qt)) * 64 + qq) * 64 + dd;
        po0 = *(const bf8*)(Op + p0);
        po1 = *(const bf8*)(Op + p0 + (size_t)512 * 64 * 64);
    }

    for (int k0 = kbeg; k0 < kend; k0 += 32) {
        g2l16(gB0h + k0, dB0h);
        g2l16(gB1h + k0, dB1h);
        g2l16(gB0l + k0, dB0l);
        g2l16(gB1l + k0, dB1l);
        {
            const int h_cur = 7 - ((k0 + aks) >> 6);
            const float w0 = c0[h_cur], w1 = c1[h_cur];
            unsigned short hi[8], lo[8];
            #pragma unroll
            for (int j = 0; j < 8; ++j) {
                const float v = w0 * bf2f((unsigned short)po0[j]) +
                                w1 * bf2f((unsigned short)po1[j]);
                split2(v, hi[j], lo[j]);
            }
            *(bf8*)&Ah[am][aks] = *(bf8*)&hi[0];
            *(bf8*)&Al[am][aks] = *(bf8*)&lo[0];
        }
        __syncthreads();

        if (k0 + 32 < kend) {
            const int e0 = k0 + 32 + aks;
            const int hh = 7 - (e0 >> 6);
            const int dd = e0 & 63;
            const size_t p0 = (((size_t)((b_row * 8 + hh) * 32 + qt)) * 64 + qq) * 64 + dd;
            po0 = *(const bf8*)(Op + p0);
            po1 = *(const bf8*)(Op + p0 + (size_t)512 * 64 * 64);
        }

        bf8 a_h[2], a_l[2], b_h[4], b_l[4];
        #pragma unroll
        for (int mi = 0; mi < 2; ++mi) {
            a_h[mi] = *(const bf8*)&Ah[wm + mi * 16 + lm][quad * 8];
            a_l[mi] = *(const bf8*)&Al[wm + mi * 16 + lm][quad * 8];
        }
        #pragma unroll
        for (int ni = 0; ni < 4; ++ni) {
            b_h[ni] = *(const bf8*)&Bh[wn + ni * 16 + lm][quad * 8];
            b_l[ni] = *(const bf8*)&Bl[wn + ni * 16 + lm][quad * 8];
        }
        #pragma unroll
        for (int mi = 0; mi < 2; ++mi)
            #pragma unroll
            for (int ni = 0; ni < 4; ++ni) {
                acc[mi][ni] = __builtin_amdgcn_mfma_f32_16x16x32_bf16(a_h[mi], b_h[ni], acc[mi][ni], 0, 0, 0);
                acc[mi][ni] = __builtin_amdgcn_mfma_f32_16x16x32_bf16(a_h[mi], b_l[ni], acc[mi][ni], 0, 0, 0);
                acc[mi][ni] = __builtin_amdgcn_mfma_f32_16x16x32_bf16(a_l[mi], b_h[ni], acc[mi][ni], 0, 0, 0);
            }
        __syncthreads();
    }

    float* dst = kz ? outp2 : outp;
    #pragma unroll
    for (int mi = 0; mi < 2; ++mi) {
        #pragma unroll
        for (int r = 0; r < 4; ++r) {
            const int m = m0 + wm + mi * 16 + quad * 4 + r;
            #pragma unroll
            for (int ni = 0; ni < 4; ++ni) {
                const int n = n0 + wn + ni * 16 + lm;
                const size_t idx = (size_t)m * En + n;
                const float extra = kz ? 0.f : (bp[n] + x[idx]);
                dst[idx] = acc[mi][ni][r] + extra;
            }
        }
    }
}

// ---------------------------------------------------------------------------
// Kernel 4 (R9-exact): LayerNorm over (outp + outp2), 1 wave per row.
// ---------------------------------------------------------------------------
__global__ __launch_bounds__(256)
void ln_kernel(const float* __restrict__ outp,
               const float* __restrict__ outp2,
               const float* __restrict__ gamma,
               const float* __restrict__ beta,
               float* __restrict__ y)
{
    const int row = blockIdx.x * 4 + (threadIdx.x >> 6);
    const int lane = threadIdx.x & 63;
    const size_t off = (size_t)row * En + lane * 8;

    float a[8], b2[8];
    *(float4*)&a[0] = *(const float4*)(outp + off);
    *(float4*)&a[4] = *(const float4*)(outp + off + 4);
    *(float4*)&b2[0] = *(const float4*)(outp2 + off);
    *(float4*)&b2[4] = *(const float4*)(outp2 + off + 4);
    #pragma unroll
    for (int j = 0; j < 8; ++j) a[j] += b2[j];

    float sum = 0.f, sq = 0.f;
    #pragma unroll
    for (int j = 0; j < 8; ++j) { sum += a[j]; sq += a[j] * a[j]; }
    #pragma unroll
    for (int off_ = 1; off_ < 64; off_ <<= 1) {
        sum += __shfl_xor(sum, off_);
        sq  += __shfl_xor(sq, off_);
    }
    const float mu = sum * (1.f / 512.f);
    const float var = sq * (1.f / 512.f) - mu * mu;
    const float rs = rsqrtf(var + 1e-5f);

    const float* g = gamma + lane * 8;
    const float* be = beta + lane * 8;
    float o[8];
    #pragma unroll
    for (int j = 0; j < 8; ++j)
        o[j] = (a[j] - mu) * rs * g[j] + be[j];
    float* yr = y + off;
    *(float4*)(yr)     = *(float4*)&o[0];
    *(float4*)(yr + 4) = *(float4*)&o[4];
}

// ---------------------------------------------------------------------------
extern "C" void kernel_launch(void* const* d_in, const int* in_sizes, int n_in,
                              void* d_out, int out_size, void* d_ws, size_t ws_size,
                              hipStream_t stream)
{
    const float* x     = (const float*)d_in[0];
    const float* Wq    = (const float*)d_in[1];
    const float* Wk    = (const float*)d_in[2];
    const float* Wv    = (const float*)d_in[3];
    const float* Wp    = (const float*)d_in[4];
    const float* bp    = (const float*)d_in[5];
    const float* gamma = (const float*)d_in[6];
    const float* beta  = (const float*)d_in[7];
    // d_in[8] = mask (int32 tril) — causal, applied analytically.

    float* ws   = (float*)d_ws;
    float* ml   = ws;                            // 131,072 floats
    float* outp = ws + XY;                       // 2M floats (8 MB)
    unsigned short* bfb = (unsigned short*)(ws + 2 * XY);
    unsigned short* xh  = bfb;
    unsigned short* xl  = bfb + XY;
    unsigned short* Wth = bfb + 2 * XY;
    unsigned short* Wtl = Wth + WT;
    unsigned short* Wph = Wtl + WT;
    unsigned short* Wpl = Wph + WP;
    unsigned short* qh  = Wpl + WP;
    unsigned short* ql  = qh + PL;
    unsigned short* kh  = ql + PL;
    unsigned short* kl  = kh + PL;
    unsigned short* vT  = kl + PL;
    unsigned short* Op = xh;                     // reuse (dead after qkv_gemm)
    float* outp2 = (float*)qh;                   // reuse (dead after attn)

    const int attn_lds = 46592;                  // 3x9216 + 18432 + 512
    hipFuncSetAttribute((const void*)attn,
                        hipFuncAttributeMaxDynamicSharedMemorySize, attn_lds);

    prep<<<dim3(1344), 256, 0, stream>>>(x, Wp, Wq, Wk, Wv,
                                         xh, xl, Wph, Wpl, Wth, Wtl);
    qkv_gemm<<<dim3(Mn / 128, 24), 256, 0, stream>>>(xh, xl, Wth, Wtl,
                                                     qh, ql, kh, kl, vT);
    attn<<<dim3(256), 512, attn_lds, stream>>>(qh, ql, kh, kl, vT, Op, ml);
    out_gemm<<<dim3(Mn / 64, En / 128, 2), 256, 0, stream>>>(Op, ml, Wph, Wpl,
                                                             bp, x, outp, outp2);
    ln_kernel<<<dim3(Mn / 4), 256, 0, stream>>>(outp, outp2, gamma, beta,
                                                (float*)d_out);
}

// Round 7
// 170.019 us; speedup vs baseline: 1.0872x; 1.0129x over previous
//
#include <hip/hip_runtime.h>

// Problem constants
constexpr int Bn = 2;
constexpr int Sn = 2048;
constexpr int En = 512;
constexpr int Hn = 8;
constexpr int Dn = 64;
constexpr int Mn = Bn * Sn;              // 4096 rows

typedef short bf8 __attribute__((ext_vector_type(8)));
typedef float f32x4 __attribute__((ext_vector_type(4)));

// element counts (ushort units) for the bf16 workspace region
constexpr size_t XY = (size_t)Mn * En;          // 2,097,152  x planes
constexpr size_t WT = (size_t)3 * En * En;      //   786,432  Wqkv transposed planes
constexpr size_t WP = (size_t)En * En;          //   262,144  Wp planes
constexpr size_t PL = (size_t)Bn * Hn * Sn * Dn;// 2,097,152  q/k/v planes
constexpr size_t MLP = (size_t)512 * 64 * 2;    // ml plane stride (floats)
constexpr size_t OPP = (size_t)512 * 64 * 64;   // Op plane stride (ushorts)

__device__ __forceinline__ unsigned short f2bf(float f) {
    unsigned int u = __float_as_uint(f);
    unsigned int r = 0x7FFFu + ((u >> 16) & 1u);
    return (unsigned short)((u + r) >> 16);
}
__device__ __forceinline__ float bf2f(unsigned short u) {
    return __uint_as_float(((unsigned int)u) << 16);
}
__device__ __forceinline__ void split2(float f, unsigned short& hi, unsigned short& lo) {
    hi = f2bf(f);
    lo = f2bf(f - bf2f(hi));
}

// global -> LDS direct copy, 16 B per lane. LDS dest is wave-uniform base +
// lane*16 (HW behavior); global source is per-lane.
__device__ __forceinline__ void g2l16(const unsigned short* g, unsigned short* l) {
    typedef __attribute__((address_space(1))) const unsigned int gu32;
    typedef __attribute__((address_space(3))) unsigned int lu32;
    __builtin_amdgcn_global_load_lds((gu32*)(unsigned long long)g,
                                     (lu32*)(unsigned int)(unsigned long long)l,
                                     16, 0, 0);
}

// ---------------------------------------------------------------------------
// Prep (fused): blocks [0,1024) presplit x; [1024,1152) presplit Wp;
// [1152,1344) transpose+split Wq/Wk/Wv -> Wt[n][k]. (R9-exact)
// ---------------------------------------------------------------------------
__global__ __launch_bounds__(256)
void prep(const float* __restrict__ x, const float* __restrict__ Wp,
          const float* __restrict__ Wq, const float* __restrict__ Wk,
          const float* __restrict__ Wv,
          unsigned short* __restrict__ xh, unsigned short* __restrict__ xl,
          unsigned short* __restrict__ Wph, unsigned short* __restrict__ Wpl,
          unsigned short* __restrict__ Wth, unsigned short* __restrict__ Wtl)
{
    __shared__ float t[64][65];
    const int bid = blockIdx.x;
    const int tid = threadIdx.x;

    if (bid < 1152) {
        const float* src = (bid < 1024) ? x : Wp;
        unsigned short* hp = (bid < 1024) ? xh : Wph;
        unsigned short* lp = (bid < 1024) ? xl : Wpl;
        const int blk = (bid < 1024) ? bid : (bid - 1024);
        const size_t base = ((size_t)blk * 256 + tid) * 8;
        float a[8];
        *(float4*)&a[0] = *(const float4*)(src + base);
        *(float4*)&a[4] = *(const float4*)(src + base + 4);
        unsigned short h[8], l[8];
        #pragma unroll
        for (int j = 0; j < 8; ++j) split2(a[j], h[j], l[j]);
        *(bf8*)(hp + base) = *(bf8*)&h[0];
        *(bf8*)(lp + base) = *(bf8*)&l[0];
        return;
    }

    const int idx = bid - 1152;           // 0..191
    const int ph = idx >> 3;              // 0..23
    const int proj = ph >> 3, h = ph & 7;
    const int e0 = (idx & 7) * 64;
    const float* W = (proj == 0) ? Wq : (proj == 1) ? Wk : Wv;
    const float* src = W + (size_t)h * En * Dn + (size_t)e0 * Dn;

    const int er = tid >> 2, cg = (tid & 3) * 16;
    #pragma unroll
    for (int c = 0; c < 4; ++c) {
        float4 v = *(const float4*)(src + (size_t)er * Dn + cg + 4 * c);
        t[er][cg + 4 * c + 0] = v.x;
        t[er][cg + 4 * c + 1] = v.y;
        t[er][cg + 4 * c + 2] = v.z;
        t[er][cg + 4 * c + 3] = v.w;
    }
    __syncthreads();

    const int d = tid >> 2, jg = (tid & 3) * 16;
    unsigned short h16[16], l16[16];
    #pragma unroll
    for (int j = 0; j < 16; ++j) split2(t[jg + j][d], h16[j], l16[j]);
    const size_t n = (size_t)proj * 512 + h * 64 + d;
    unsigned short* dh = Wth + n * En + e0 + jg;
    unsigned short* dl = Wtl + n * En + e0 + jg;
    *(bf8*)dh       = *(bf8*)&h16[0];
    *(bf8*)(dh + 8) = *(bf8*)&h16[8];
    *(bf8*)dl       = *(bf8*)&l16[0];
    *(bf8*)(dl + 8) = *(bf8*)&l16[8];
}

// ---------------------------------------------------------------------------
// Kernel 1 (R14-exact): fused QKV projection, 128x64 tiles, double-buffered
// global_load_lds staging. LDS 48 KB x 3 blocks/CU.
// ---------------------------------------------------------------------------
__global__ __launch_bounds__(256)
void qkv_gemm(const unsigned short* __restrict__ xh,
              const unsigned short* __restrict__ xl,
              const unsigned short* __restrict__ Wth,
              const unsigned short* __restrict__ Wtl,
              unsigned short* __restrict__ qh_g,
              unsigned short* __restrict__ ql_g,
              unsigned short* __restrict__ kh_g,
              unsigned short* __restrict__ kl_g,
              unsigned short* __restrict__ vT_g)
{
    __shared__ __align__(16) unsigned char smraw[49152];
    unsigned short* ldsAh = (unsigned short*)smraw;
    unsigned short* ldsAl = ldsAh + 8192;
    unsigned short* ldsBh = ldsAl + 8192;
    unsigned short* ldsBl = ldsBh + 4096;
    float (*Cf)[68] = (float(*)[68])(smraw);   // 64 x 68 fp32 (epilogue reuse)

    const int tid = threadIdx.x;
    const int m0 = blockIdx.x * 128;
    const int ny = blockIdx.y;            // 0..23
    const int proj = ny >> 3, h = ny & 7;

    const int wave = tid >> 6, lane = tid & 63;
    const int wm = (wave >> 1) * 64, wn = (wave & 1) * 32;
    const int lm = lane & 15, quad = lane >> 4;

    const int l4r = lane >> 2;            // 0..15
    const int l4c = (lane & 3) * 8;       // ushort col
    const unsigned short* gAh0 = xh + (size_t)(m0 + wave * 32 + l4r) * En + l4c;
    const unsigned short* gAh1 = gAh0 + (size_t)16 * En;
    const unsigned short* gAl0 = xl + (size_t)(m0 + wave * 32 + l4r) * En + l4c;
    const unsigned short* gAl1 = gAl0 + (size_t)16 * En;
    const unsigned short* gBh  = Wth + (size_t)(ny * 64 + wave * 16 + l4r) * En + l4c;
    const unsigned short* gBl  = Wtl + (size_t)(ny * 64 + wave * 16 + l4r) * En + l4c;
    const int offA = wave * 1024;
    const int offB = wave * 512;

    f32x4 acc[4][2];
    #pragma unroll
    for (int i = 0; i < 4; ++i)
        #pragma unroll
        for (int j = 0; j < 2; ++j) acc[i][j] = (f32x4){0.f, 0.f, 0.f, 0.f};

    g2l16(gAh0, ldsAh + offA);
    g2l16(gAh1, ldsAh + offA + 512);
    g2l16(gAl0, ldsAl + offA);
    g2l16(gAl1, ldsAl + offA + 512);
    g2l16(gBh,  ldsBh + offB);
    g2l16(gBl,  ldsBl + offB);

    int cur = 0;
    for (int k0 = 0; k0 < En; k0 += 32) {
        __syncthreads();
        const int nxt = cur ^ 1;
        if (k0 + 32 < En) {
            g2l16(gAh0 + k0 + 32, ldsAh + nxt * 4096 + offA);
            g2l16(gAh1 + k0 + 32, ldsAh + nxt * 4096 + offA + 512);
            g2l16(gAl0 + k0 + 32, ldsAl + nxt * 4096 + offA);
            g2l16(gAl1 + k0 + 32, ldsAl + nxt * 4096 + offA + 512);
            g2l16(gBh + k0 + 32,  ldsBh + nxt * 2048 + offB);
            g2l16(gBl + k0 + 32,  ldsBl + nxt * 2048 + offB);
        }

        const unsigned short* bAh = ldsAh + cur * 4096;
        const unsigned short* bAl = ldsAl + cur * 4096;
        const unsigned short* bBh = ldsBh + cur * 2048;
        const unsigned short* bBl = ldsBl + cur * 2048;
        bf8 a_h[4], a_l[4], b_h[2], b_l[2];
        #pragma unroll
        for (int mi = 0; mi < 4; ++mi) {
            a_h[mi] = *(const bf8*)(bAh + (wm + mi * 16 + lm) * 32 + quad * 8);
            a_l[mi] = *(const bf8*)(bAl + (wm + mi * 16 + lm) * 32 + quad * 8);
        }
        #pragma unroll
        for (int ni = 0; ni < 2; ++ni) {
            b_h[ni] = *(const bf8*)(bBh + (wn + ni * 16 + lm) * 32 + quad * 8);
            b_l[ni] = *(const bf8*)(bBl + (wn + ni * 16 + lm) * 32 + quad * 8);
        }
        #pragma unroll
        for (int mi = 0; mi < 4; ++mi)
            #pragma unroll
            for (int ni = 0; ni < 2; ++ni) {
                acc[mi][ni] = __builtin_amdgcn_mfma_f32_16x16x32_bf16(a_h[mi], b_h[ni], acc[mi][ni], 0, 0, 0);
                acc[mi][ni] = __builtin_amdgcn_mfma_f32_16x16x32_bf16(a_h[mi], b_l[ni], acc[mi][ni], 0, 0, 0);
                acc[mi][ni] = __builtin_amdgcn_mfma_f32_16x16x32_bf16(a_l[mi], b_h[ni], acc[mi][ni], 0, 0, 0);
            }
        cur = nxt;
    }
    __syncthreads();

    if (proj < 2) {
        unsigned short* hp = (proj == 0) ? qh_g : kh_g;
        unsigned short* lp = (proj == 0) ? ql_g : kl_g;
        #pragma unroll
        for (int p = 0; p < 2; ++p) {
            if ((wave >> 1) == p) {
                #pragma unroll
                for (int mi = 0; mi < 4; ++mi)
                    #pragma unroll
                    for (int ni = 0; ni < 2; ++ni)
                        #pragma unroll
                        for (int r = 0; r < 4; ++r)
                            Cf[mi * 16 + quad * 4 + r][wn + ni * 16 + lm] = acc[mi][ni][r];
            }
            __syncthreads();
            {
                const int lr = tid & 63;
                const int cg = (tid >> 6) * 16;   // wave-uniform d-chunk
                const int m = m0 + p * 64 + lr;
                const int b = m >> 11, s = m & 2047;
                unsigned short hi[16], lo[16];
                #pragma unroll
                for (int j4 = 0; j4 < 4; ++j4) {
                    float4 v = *(const float4*)&Cf[lr][cg + 4 * j4];
                    split2(v.x, hi[4 * j4 + 0], lo[4 * j4 + 0]);
                    split2(v.y, hi[4 * j4 + 1], lo[4 * j4 + 1]);
                    split2(v.z, hi[4 * j4 + 2], lo[4 * j4 + 2]);
                    split2(v.w, hi[4 * j4 + 3], lo[4 * j4 + 3]);
                }
                const size_t base = (((size_t)(b * Hn + h) * Sn + s) * Dn) + cg;
                *(bf8*)(hp + base)     = *(bf8*)&hi[0];
                *(bf8*)(hp + base + 8) = *(bf8*)&hi[8];
                *(bf8*)(lp + base)     = *(bf8*)&lo[0];
                *(bf8*)(lp + base + 8) = *(bf8*)&lo[8];
            }
            __syncthreads();
        }
    } else {
        #pragma unroll
        for (int mi = 0; mi < 4; ++mi) {
            const int s0 = m0 + wm + mi * 16 + quad * 4;
            const int b = s0 >> 11, s = s0 & 2047;
            #pragma unroll
            for (int ni = 0; ni < 2; ++ni) {
                const int d = wn + ni * 16 + lm;
                ushort4 pk;
                pk.x = f2bf(acc[mi][ni][0]);
                pk.y = f2bf(acc[mi][ni][1]);
                pk.z = f2bf(acc[mi][ni][2]);
                pk.w = f2bf(acc[mi][ni][3]);
                *(ushort4*)(vT_g + ((size_t)(b * Hn + h) * Dn + d) * Sn + s) = pk;
            }
        }
    }
}

// ---------------------------------------------------------------------------
// Kernel 2 (R16): MFMA flash attention, QBLK=128, 4-WAY K-split for 2x TLP.
// R15 structure with the cvt_pk inline-asm removed (scalar f2bf pack, as in
// R14) and prefetch regs zero-initialized. Quarters j=0..3 of the causal
// range [0, 2qt+2); block (bh,qp,sb) runs (qt=qp, j=sb) then
// (qt=15-qp, j=3-sb) -> 8-9 tiles/block uniform. Grid 512 = 2 blocks/CU
// (16 waves/CU). out_gemm does the 4-way combine.
// ---------------------------------------------------------------------------
__global__ __launch_bounds__(512, 4)
void attn(const unsigned short* __restrict__ qh_g,
          const unsigned short* __restrict__ ql_g,
          const unsigned short* __restrict__ kh_g,
          const unsigned short* __restrict__ kl_g,
          const unsigned short* __restrict__ vT_g,
          unsigned short* __restrict__ Op,
          float* __restrict__ ml)
{
    extern __shared__ unsigned short sm[];
    unsigned short (*khs)[72] = (unsigned short(*)[72])(sm);          // [64][72] hi
    unsigned short (*kls)[72] = (unsigned short(*)[72])(sm + 4608);   // [64][72] lo
    unsigned short (*vTs)[72] = (unsigned short(*)[72])(sm + 9216);   // [64][72] d-major
    unsigned short (*pts)[72] = (unsigned short(*)[72])(sm + 13824);  // [128][72]
    float* alf = (float*)(sm + 23040);                                // [128]

    const int bidx = blockIdx.x;          // 0..511
    const int xcd = bidx & 7;
    const int g = bidx >> 3;              // 0..63
    const int bh = xcd * 2 + (g & 1);     // 2 bh per XCD (K/V L2-local)
    const int p2 = g >> 1;                // 0..31
    const int qp = p2 & 15;
    const int sb = p2 >> 4;               // 0..1

    const int tid = threadIdx.x;
    const int wave = tid >> 6, lane = tid & 63;
    const int quad = lane >> 4, lq = lane & 15;
    const int wq = wave >> 2;             // 64-row subgroup (0/1)
    const int w4 = wave & 3;              // wave within subgroup

    const unsigned short* khb = kh_g + (size_t)bh * Sn * Dn;
    const unsigned short* klb = kl_g + (size_t)bh * Sn * Dn;
    const unsigned short* vTb = vT_g + (size_t)bh * Dn * Sn;

    const int srow = tid & 63;
    const int sdg  = tid >> 6;            // 0..7, 8-ushort slice

    #pragma unroll 1
    for (int ph = 0; ph < 2; ++ph) {
        const int qt = ph ? (15 - qp) : qp;
        const int j  = ph ? (3 - sb) : sb;
        const int n  = 2 * qt + 2;
        const int its = (j * n) >> 2;
        const int ite = ((j + 1) * n) >> 2;
        const int qt64 = 2 * qt + wq;     // global 64-row q-tile index
        const int pslot = j * 512 + bh * 32 + qt64;
        const int dt = qt64;              // diagonal t-tile for this wave

        bf8 qfh[2], qfl[2];
        {
            const size_t qoff = ((size_t)bh * Sn + (size_t)qt * 128 + wave * 16 + lq) * Dn;
            #pragma unroll
            for (int c = 0; c < 2; ++c) {
                qfh[c] = *(const bf8*)(qh_g + qoff + c * 32 + quad * 8);
                qfl[c] = *(const bf8*)(ql_g + qoff + c * 32 + quad * 8);
            }
        }

        f32x4 accO[4];
        #pragma unroll
        for (int nj = 0; nj < 4; ++nj) accO[nj] = (f32x4){0.f, 0.f, 0.f, 0.f};
        float m = -1e30f, l = 0.f;

        bf8 pk0 = {0, 0, 0, 0, 0, 0, 0, 0};
        bf8 pl0 = {0, 0, 0, 0, 0, 0, 0, 0};
        bf8 pv0 = {0, 0, 0, 0, 0, 0, 0, 0};
        if (its < ite) {
            const int t0 = its * 64;
            pk0 = *(const bf8*)(khb + (size_t)(t0 + srow) * Dn + sdg * 8);
            pl0 = *(const bf8*)(klb + (size_t)(t0 + srow) * Dn + sdg * 8);
            pv0 = *(const bf8*)(vTb + (size_t)srow * Sn + t0 + sdg * 8);
        }

        for (int it = its; it < ite; ++it) {
            __syncthreads();
            *(bf8*)&khs[srow][sdg * 8] = pk0;
            *(bf8*)&kls[srow][sdg * 8] = pl0;
            *(bf8*)&vTs[srow][sdg * 8] = pv0;
            __syncthreads();

            if (it + 1 < ite) {
                const int t1 = (it + 1) * 64;
                pk0 = *(const bf8*)(khb + (size_t)(t1 + srow) * Dn + sdg * 8);
                pl0 = *(const bf8*)(klb + (size_t)(t1 + srow) * Dn + sdg * 8);
                pv0 = *(const bf8*)(vTb + (size_t)srow * Sn + t1 + sdg * 8);
            }

            if (it > dt) continue;        // fully-masked tile for this wave

            f32x4 accS[4];
            #pragma unroll
            for (int mi = 0; mi < 4; ++mi) accS[mi] = (f32x4){0.f, 0.f, 0.f, 0.f};
            __builtin_amdgcn_s_setprio(1);
            #pragma unroll
            for (int mi = 0; mi < 4; ++mi) {
                #pragma unroll
                for (int c = 0; c < 2; ++c) {
                    bf8 ah = *(const bf8*)&khs[mi * 16 + lq][c * 32 + quad * 8];
                    bf8 al = *(const bf8*)&kls[mi * 16 + lq][c * 32 + quad * 8];
                    accS[mi] = __builtin_amdgcn_mfma_f32_16x16x32_bf16(ah, qfh[c], accS[mi], 0, 0, 0);
                    accS[mi] = __builtin_amdgcn_mfma_f32_16x16x32_bf16(ah, qfl[c], accS[mi], 0, 0, 0);
                    accS[mi] = __builtin_amdgcn_mfma_f32_16x16x32_bf16(al, qfh[c], accS[mi], 0, 0, 0);
                }
            }
            __builtin_amdgcn_s_setprio(0);

            if (it == dt) {
                const int qrel = w4 * 16 + lq;    // q within 64-row subgroup
                #pragma unroll
                for (int mi = 0; mi < 4; ++mi)
                    #pragma unroll
                    for (int r = 0; r < 4; ++r)
                        if (mi * 16 + quad * 4 + r > qrel) accS[mi][r] = -INFINITY;
            }

            float mt;
            {
                float t0 = fmaxf(fmaxf(accS[0][0], accS[0][1]), fmaxf(accS[0][2], accS[0][3]));
                float t1 = fmaxf(fmaxf(accS[1][0], accS[1][1]), fmaxf(accS[1][2], accS[1][3]));
                float t2 = fmaxf(fmaxf(accS[2][0], accS[2][1]), fmaxf(accS[2][2], accS[2][3]));
                float t3 = fmaxf(fmaxf(accS[3][0], accS[3][1]), fmaxf(accS[3][2], accS[3][3]));
                mt = fmaxf(fmaxf(t0, t1), fmaxf(t2, t3));
            }
            mt = fmaxf(mt, __shfl_xor(mt, 16));
            mt = fmaxf(mt, __shfl_xor(mt, 32));

            const bool defer = __all(mt <= m + 12.f);
            float mref, alpha = 1.f;
            if (defer) {
                mref = m;
            } else {
                mref = fmaxf(m, mt);
                alpha = __expf(m - mref);
            }

            float ls = 0.f;
            #pragma unroll
            for (int mi = 0; mi < 4; ++mi)
                #pragma unroll
                for (int r = 0; r < 4; ++r) {
                    const float p = __expf(accS[mi][r] - mref);
                    accS[mi][r] = p;
                    ls += p;
                }
            ls += __shfl_xor(ls, 16);
            ls += __shfl_xor(ls, 32);
            if (defer) {
                l += ls;
            } else {
                l = l * alpha + ls;
                m = mref;
            }

            #pragma unroll
            for (int mi = 0; mi < 4; ++mi) {
                ushort4 pk;
                pk.x = f2bf(accS[mi][0]);
                pk.y = f2bf(accS[mi][1]);
                pk.z = f2bf(accS[mi][2]);
                pk.w = f2bf(accS[mi][3]);
                *(ushort4*)&pts[wave * 16 + lq][mi * 16 + quad * 4] = pk;
            }

            if (!defer) {
                if (quad == 0) alf[wave * 16 + lq] = alpha;
                float4 al4 = *(const float4*)&alf[wave * 16 + quad * 4];
                #pragma unroll
                for (int nj = 0; nj < 4; ++nj) {
                    accO[nj][0] *= al4.x;
                    accO[nj][1] *= al4.y;
                    accO[nj][2] *= al4.z;
                    accO[nj][3] *= al4.w;
                }
            }

            __builtin_amdgcn_s_setprio(1);
            #pragma unroll
            for (int c = 0; c < 2; ++c) {
                bf8 pf = *(const bf8*)&pts[wave * 16 + lq][c * 32 + quad * 8];
                #pragma unroll
                for (int nj = 0; nj < 4; ++nj) {
                    bf8 vf = *(const bf8*)&vTs[nj * 16 + lq][c * 32 + quad * 8];
                    accO[nj] = __builtin_amdgcn_mfma_f32_16x16x32_bf16(pf, vf, accO[nj], 0, 0, 0);
                }
            }
            __builtin_amdgcn_s_setprio(0);
        }

        if (quad == 0) {
            const size_t mi_ = ((size_t)pslot * 64 + w4 * 16 + lq) * 2;
            ml[mi_]     = m;
            ml[mi_ + 1] = l;
        }
        #pragma unroll
        for (int r = 0; r < 4; ++r) {
            const int q = w4 * 16 + quad * 4 + r;
            unsigned short* dst = Op + ((size_t)pslot * 64 + q) * 64;
            #pragma unroll
            for (int nj = 0; nj < 4; ++nj)
                dst[nj * 16 + lq] = f2bf(accO[nj][r]);
        }
    }
}

// ---------------------------------------------------------------------------
// Kernel 3 (R16): fused combine + out-projection + residual, split-K=2,
// 4-WAY attention-partial combine (only the 4 heads this kz uses).
// B planes via global_load_lds; A reg-staged with next-step prefetch.
// Grid (64, 4, 2) = 512 blocks (2/CU).
// ---------------------------------------------------------------------------
__global__ __launch_bounds__(256)
void out_gemm(const unsigned short* __restrict__ Op,
              const float* __restrict__ ml,
              const unsigned short* __restrict__ Wph,
              const unsigned short* __restrict__ Wpl,
              const float* __restrict__ bp,
              const float* __restrict__ x,
              float* __restrict__ outp,
              float* __restrict__ outp2)
{
    __shared__ unsigned short Ah[64][40], Al[64][40];
    __shared__ __align__(16) unsigned short Bh[128][32], Bl[128][32];

    const int tid = threadIdx.x;
    const int m0 = blockIdx.x * 64;
    const int n0 = blockIdx.y * 128;
    const int kz = blockIdx.z;
    const int kbeg = kz * 256, kend = kbeg + 256;

    const int wave = tid >> 6, lane = tid & 63;
    const int wm = (wave >> 1) * 32, wn = (wave & 1) * 64;
    const int lm = lane & 15, quad = lane >> 4;

    const int am = tid >> 2;
    const int aks = (tid & 3) * 8;
    const int m_row = m0 + am;
    const int b_row = m_row >> 11, s_row = m_row & 2047;
    const int qt = s_row >> 6, qq = s_row & 63;

    // 4-way combine scales for the 4 heads this kz covers:
    // kz=0 -> heads 4..7, kz=1 -> heads 0..3; local index hl = h & 3.
    float c0[4], c1[4], c2[4], c3[4];
    #pragma unroll
    for (int hl = 0; hl < 4; ++hl) {
        const int h = hl + (kz ? 0 : 4);
        const size_t base0 = (((size_t)(b_row * 8 + h) * 32 + qt) * 64 + qq) * 2;
        float mi_[4], li_[4];
        #pragma unroll
        for (int i = 0; i < 4; ++i) {
            mi_[i] = ml[base0 + i * MLP];
            li_[i] = ml[base0 + i * MLP + 1];
        }
        const float mn = fmaxf(fmaxf(mi_[0], mi_[1]), fmaxf(mi_[2], mi_[3]));
        const float a0 = __expf(mi_[0] - mn), a1 = __expf(mi_[1] - mn);
        const float a2 = __expf(mi_[2] - mn), a3 = __expf(mi_[3] - mn);
        const float inv = 1.f / (a0 * li_[0] + a1 * li_[1] + a2 * li_[2] + a3 * li_[3]);
        c0[hl] = a0 * inv;
        c1[hl] = a1 * inv;
        c2[hl] = a2 * inv;
        c3[hl] = a3 * inv;
    }

    const int l4r = lane >> 2;
    const int l4c = (lane & 3) * 8;
    const unsigned short* gB0h = Wph + (size_t)(n0 + wave * 32 + l4r) * En + l4c;
    const unsigned short* gB1h = gB0h + (size_t)16 * En;
    const unsigned short* gB0l = Wpl + (size_t)(n0 + wave * 32 + l4r) * En + l4c;
    const unsigned short* gB1l = gB0l + (size_t)16 * En;
    unsigned short* dB0h = &Bh[0][0] + wave * 1024;
    unsigned short* dB1h = dB0h + 512;
    unsigned short* dB0l = &Bl[0][0] + wave * 1024;
    unsigned short* dB1l = dB0l + 512;

    f32x4 acc[2][4];
    #pragma unroll
    for (int i = 0; i < 2; ++i)
        #pragma unroll
        for (int j = 0; j < 4; ++j) acc[i][j] = (f32x4){0.f, 0.f, 0.f, 0.f};

    bf8 po0, po1, po2, po3;
    {
        const int e0 = kbeg + aks;
        const int hh = 7 - (e0 >> 6);
        const int dd = e0 & 63;
        const size_t p0 = (((size_t)((b_row * 8 + hh) * 32 + qt)) * 64 + qq) * 64 + dd;
        po0 = *(const bf8*)(Op + p0);
        po1 = *(const bf8*)(Op + p0 + OPP);
        po2 = *(const bf8*)(Op + p0 + 2 * OPP);
        po3 = *(const bf8*)(Op + p0 + 3 * OPP);
    }

    for (int k0 = kbeg; k0 < kend; k0 += 32) {
        g2l16(gB0h + k0, dB0h);
        g2l16(gB1h + k0, dB1h);
        g2l16(gB0l + k0, dB0l);
        g2l16(gB1l + k0, dB1l);
        {
            const int hidx = (7 - ((k0 + aks) >> 6)) & 3;
            const float w0 = c0[hidx], w1 = c1[hidx];
            const float w2 = c2[hidx], w3 = c3[hidx];
            unsigned short hi[8], lo[8];
            #pragma unroll
            for (int j = 0; j < 8; ++j) {
                const float v = w0 * bf2f((unsigned short)po0[j]) +
                                w1 * bf2f((unsigned short)po1[j]) +
                                w2 * bf2f((unsigned short)po2[j]) +
                                w3 * bf2f((unsigned short)po3[j]);
                split2(v, hi[j], lo[j]);
            }
            *(bf8*)&Ah[am][aks] = *(bf8*)&hi[0];
            *(bf8*)&Al[am][aks] = *(bf8*)&lo[0];
        }
        __syncthreads();

        if (k0 + 32 < kend) {
            const int e0 = k0 + 32 + aks;
            const int hh = 7 - (e0 >> 6);
            const int dd = e0 & 63;
            const size_t p0 = (((size_t)((b_row * 8 + hh) * 32 + qt)) * 64 + qq) * 64 + dd;
            po0 = *(const bf8*)(Op + p0);
            po1 = *(const bf8*)(Op + p0 + OPP);
            po2 = *(const bf8*)(Op + p0 + 2 * OPP);
            po3 = *(const bf8*)(Op + p0 + 3 * OPP);
        }

        bf8 a_h[2], a_l[2], b_h[4], b_l[4];
        #pragma unroll
        for (int mi = 0; mi < 2; ++mi) {
            a_h[mi] = *(const bf8*)&Ah[wm + mi * 16 + lm][quad * 8];
            a_l[mi] = *(const bf8*)&Al[wm + mi * 16 + lm][quad * 8];
        }
        #pragma unroll
        for (int ni = 0; ni < 4; ++ni) {
            b_h[ni] = *(const bf8*)&Bh[wn + ni * 16 + lm][quad * 8];
            b_l[ni] = *(const bf8*)&Bl[wn + ni * 16 + lm][quad * 8];
        }
        #pragma unroll
        for (int mi = 0; mi < 2; ++mi)
            #pragma unroll
            for (int ni = 0; ni < 4; ++ni) {
                acc[mi][ni] = __builtin_amdgcn_mfma_f32_16x16x32_bf16(a_h[mi], b_h[ni], acc[mi][ni], 0, 0, 0);
                acc[mi][ni] = __builtin_amdgcn_mfma_f32_16x16x32_bf16(a_h[mi], b_l[ni], acc[mi][ni], 0, 0, 0);
                acc[mi][ni] = __builtin_amdgcn_mfma_f32_16x16x32_bf16(a_l[mi], b_h[ni], acc[mi][ni], 0, 0, 0);
            }
        __syncthreads();
    }

    float* dst = kz ? outp2 : outp;
    #pragma unroll
    for (int mi = 0; mi < 2; ++mi) {
        #pragma unroll
        for (int r = 0; r < 4; ++r) {
            const int m = m0 + wm + mi * 16 + quad * 4 + r;
            #pragma unroll
            for (int ni = 0; ni < 4; ++ni) {
                const int n = n0 + wn + ni * 16 + lm;
                const size_t idx = (size_t)m * En + n;
                const float extra = kz ? 0.f : (bp[n] + x[idx]);
                dst[idx] = acc[mi][ni][r] + extra;
            }
        }
    }
}

// ---------------------------------------------------------------------------
// Kernel 4 (R9-exact): LayerNorm over (outp + outp2), 1 wave per row.
// ---------------------------------------------------------------------------
__global__ __launch_bounds__(256)
void ln_kernel(const float* __restrict__ outp,
               const float* __restrict__ outp2,
               const float* __restrict__ gamma,
               const float* __restrict__ beta,
               float* __restrict__ y)
{
    const int row = blockIdx.x * 4 + (threadIdx.x >> 6);
    const int lane = threadIdx.x & 63;
    const size_t off = (size_t)row * En + lane * 8;

    float a[8], b2[8];
    *(float4*)&a[0] = *(const float4*)(outp + off);
    *(float4*)&a[4] = *(const float4*)(outp + off + 4);
    *(float4*)&b2[0] = *(const float4*)(outp2 + off);
    *(float4*)&b2[4] = *(const float4*)(outp2 + off + 4);
    #pragma unroll
    for (int j = 0; j < 8; ++j) a[j] += b2[j];

    float sum = 0.f, sq = 0.f;
    #pragma unroll
    for (int j = 0; j < 8; ++j) { sum += a[j]; sq += a[j] * a[j]; }
    #pragma unroll
    for (int off_ = 1; off_ < 64; off_ <<= 1) {
        sum += __shfl_xor(sum, off_);
        sq  += __shfl_xor(sq, off_);
    }
    const float mu = sum * (1.f / 512.f);
    const float var = sq * (1.f / 512.f) - mu * mu;
    const float rs = rsqrtf(var + 1e-5f);

    const float* g = gamma + lane * 8;
    const float* be = beta + lane * 8;
    float o[8];
    #pragma unroll
    for (int j = 0; j < 8; ++j)
        o[j] = (a[j] - mu) * rs * g[j] + be[j];
    float* yr = y + off;
    *(float4*)(yr)     = *(float4*)&o[0];
    *(float4*)(yr + 4) = *(float4*)&o[4];
}

// ---------------------------------------------------------------------------
extern "C" void kernel_launch(void* const* d_in, const int* in_sizes, int n_in,
                              void* d_out, int out_size, void* d_ws, size_t ws_size,
                              hipStream_t stream)
{
    const float* x     = (const float*)d_in[0];
    const float* Wq    = (const float*)d_in[1];
    const float* Wk    = (const float*)d_in[2];
    const float* Wv    = (const float*)d_in[3];
    const float* Wp    = (const float*)d_in[4];
    const float* bp    = (const float*)d_in[5];
    const float* gamma = (const float*)d_in[6];
    const float* beta  = (const float*)d_in[7];
    // d_in[8] = mask (int32 tril) — causal, applied analytically.

    float* ws   = (float*)d_ws;
    float* ml   = ws;                            // 4 planes x 512x64x2 = 262,144 floats
    float* outp = ws + XY;                       // 2M floats (8 MB)
    unsigned short* bfb = (unsigned short*)(ws + 2 * XY);
    unsigned short* xh  = bfb;
    unsigned short* xl  = bfb + XY;
    unsigned short* Wth = bfb + 2 * XY;
    unsigned short* Wtl = Wth + WT;
    unsigned short* Wph = Wtl + WT;
    unsigned short* Wpl = Wph + WP;
    unsigned short* qh  = Wpl + WP;
    unsigned short* ql  = qh + PL;
    unsigned short* kh  = ql + PL;
    unsigned short* kl  = kh + PL;
    unsigned short* vT  = kl + PL;
    unsigned short* Op  = vT + PL;               // 4 planes x 2.1M = 8.4M ushorts
    float* outp2 = (float*)qh;                   // reuse (dead after attn)

    const int attn_lds = 46592;                  // 3x9216 + 18432 + 512
    hipFuncSetAttribute((const void*)attn,
                        hipFuncAttributeMaxDynamicSharedMemorySize, attn_lds);

    prep<<<dim3(1344), 256, 0, stream>>>(x, Wp, Wq, Wk, Wv,
                                         xh, xl, Wph, Wpl, Wth, Wtl);
    qkv_gemm<<<dim3(Mn / 128, 24), 256, 0, stream>>>(xh, xl, Wth, Wtl,
                                                     qh, ql, kh, kl, vT);
    attn<<<dim3(512), 512, attn_lds, stream>>>(qh, ql, kh, kl, vT, Op, ml);
    out_gemm<<<dim3(Mn / 64, En / 128, 2), 256, 0, stream>>>(Op, ml, Wph, Wpl,
                                                             bp, x, outp, outp2);
    ln_kernel<<<dim3(Mn / 4), 256, 0, stream>>>(outp, outp2, gamma, beta,
                                                (float*)d_out);
}